// Round 6
// baseline (518.265 us; speedup 1.0000x reference)
//
#include <hip/hip_runtime.h>
#include <hip/hip_bf16.h>

#define D 256
#define CH 8192  // edges per count/scatter block

typedef __attribute__((ext_vector_type(8))) short bf16x8;
typedef __attribute__((ext_vector_type(4))) float f32x4;

static __device__ __forceinline__ unsigned int f2bf(float f) {
  __hip_bfloat16 b = __float2bfloat16(f);
  return (unsigned int)*reinterpret_cast<unsigned short*>(&b);
}
static __device__ __forceinline__ float u2f(unsigned int u) {
  return __uint_as_float(u);
}

static __device__ __forceinline__ void acc8w(float* acc, uint4 v, float wt) {
  acc[0] += wt * u2f(v.x << 16);
  acc[1] += wt * u2f(v.x & 0xffff0000u);
  acc[2] += wt * u2f(v.y << 16);
  acc[3] += wt * u2f(v.y & 0xffff0000u);
  acc[4] += wt * u2f(v.z << 16);
  acc[5] += wt * u2f(v.z & 0xffff0000u);
  acc[6] += wt * u2f(v.w << 16);
  acc[7] += wt * u2f(v.w & 0xffff0000u);
}

// ============ FAST BUILD: deterministic counting-sort CSR ============

__global__ __launch_bounds__(256) void fused_prep_kernel(
    const int* __restrict__ row, const float* __restrict__ x, const float* __restrict__ W,
    uint4* __restrict__ xb0, uint4* __restrict__ xb1, __hip_bfloat16* __restrict__ Wt,
    int* __restrict__ counts, int E, int NB, int nblk, int total8, int convb) {
  __shared__ int hist[2048];
  int bid = blockIdx.x, tid = threadIdx.x;
  if (bid < nblk) {
    for (int t = tid; t < NB; t += 256) hist[t] = 0;
    __syncthreads();
    int e0 = bid * CH, e1 = min(E, e0 + CH);
    for (int e = e0 + tid; e < e1; e += 256) atomicAdd(&hist[row[e] >> 6], 1);
    __syncthreads();
    for (int t = tid; t < NB; t += 256) counts[(size_t)bid * NB + t] = hist[t];
  } else if (bid < nblk + convb) {
    int idx = (bid - nblk) * 256 + tid;
    if (idx < total8) {
      int j = idx >> 5, k8 = idx & 31;
      const float4* x4 = reinterpret_cast<const float4*>(x);
      float4 a = x4[(size_t)idx * 2], bb = x4[(size_t)idx * 2 + 1];
      uint4 o;
      o.x = f2bf(a.x) | (f2bf(a.y) << 16);
      o.y = f2bf(a.z) | (f2bf(a.w) << 16);
      o.z = f2bf(bb.x) | (f2bf(bb.y) << 16);
      o.w = f2bf(bb.z) | (f2bf(bb.w) << 16);
      uint4* dst = (k8 < 16) ? xb0 : xb1;
      dst[(size_t)j * 16 + (k8 & 15)] = o;
    }
  } else {
    int n = bid - nblk - convb;  // 0..D-1
    Wt[n * D + tid] = __float2bfloat16(W[tid * D + n]);
  }
}

__global__ void colscan_kernel(int* counts, int* total, int NB, int nblk) {
  int t = blockIdx.x * 256 + threadIdx.x;
  if (t >= NB) return;
  int run = 0;
#pragma unroll 4
  for (int blk = 0; blk < nblk; ++blk) {
    size_t idx = (size_t)blk * NB + t;
    int c = counts[idx];
    counts[idx] = run;
    run += c;
  }
  total[t] = run;
}

__global__ void bucket_scan_kernel(const int* __restrict__ total, int* __restrict__ bucket_base,
                                   int NB) {
  __shared__ int a[2048], b2[2048];
  int t = threadIdx.x;  // 1024 threads
  for (int k = 0; k < 2; ++k) {
    int i = t + k * 1024;
    a[i] = (i < NB) ? total[i] : 0;
  }
  __syncthreads();
  int* cur = a;
  int* nxt = b2;
  for (int off = 1; off < 2048; off <<= 1) {
    for (int k = 0; k < 2; ++k) {
      int i = t + k * 1024;
      int v = cur[i];
      if (i >= off) v += cur[i - off];
      nxt[i] = v;
    }
    __syncthreads();
    int* tmp = cur; cur = nxt; nxt = tmp;
  }
  if (t == 0) bucket_base[0] = 0;
  for (int k = 0; k < 2; ++k) {
    int i = t + k * 1024;
    if (i < NB) bucket_base[i + 1] = cur[i];
  }
}

__global__ __launch_bounds__(256) void scatter_kernel(
    const int* __restrict__ row, const int* __restrict__ col, const int* __restrict__ counts,
    const int* __restrict__ bucket_base, unsigned int* __restrict__ sorted, int E, int NB) {
  __shared__ int base[2048];
  __shared__ int cur[2048];
  int bid = blockIdx.x, tid = threadIdx.x;
  for (int t = tid; t < NB; t += 256) {
    base[t] = bucket_base[t] + counts[(size_t)bid * NB + t];
    cur[t] = 0;
  }
  __syncthreads();
  int e0 = bid * CH, e1 = min(E, e0 + CH);
  for (int e = e0 + tid; e < e1; e += 256) {
    int r = row[e], c = col[e];
    int b = r >> 6;
    int p = base[b] + atomicAdd(&cur[b], 1);
    sorted[p] = ((unsigned int)(r & 63) << 17) | (unsigned int)c;
  }
}

__global__ __launch_bounds__(256) void bucket_csr_kernel(
    const unsigned int* __restrict__ sorted, const int* __restrict__ bucket_base,
    int* __restrict__ offsets, float* __restrict__ dinv, int* __restrict__ csr_col,
    int N, int E, int NB, int ncb) {
  __shared__ int cnt[1024];
  int b = blockIdx.x, tid = threadIdx.x;
  int lo = bucket_base[b], hi = bucket_base[b + 1];
  int slots = 64 * ncb;
  for (int t = tid; t < slots; t += 256) cnt[t] = 0;
  __syncthreads();
  for (int e = lo + tid; e < hi; e += 256) {
    unsigned int v = sorted[e];
    atomicAdd(&cnt[(v >> 17) * ncb + ((v & 0x1FFFFu) >> 13)], 1);
  }
  __syncthreads();
  if (tid == 0) {
    int run = 0;
    for (int i2 = 0; i2 < slots; ++i2) {
      int t2 = cnt[i2];
      cnt[i2] = run;
      run += t2;
    }
  }
  __syncthreads();
  if (tid < 64) {
    int gr = b * 64 + tid;
    if (gr < N) {
      int start = cnt[tid * ncb];
      int nxt = (tid == 63) ? (hi - lo) : cnt[(tid + 1) * ncb];
      int dg = nxt - start;
      offsets[gr] = lo + start;
      dinv[gr] = (dg > 0) ? rsqrtf((float)dg) : 0.f;
    }
  }
  if (b == NB - 1 && tid == 0) offsets[N] = E;
  __syncthreads();
  for (int e = lo + tid; e < hi; e += 256) {
    unsigned int v = sorted[e];
    int p = lo + atomicAdd(&cnt[(v >> 17) * ncb + ((v & 0x1FFFFu) >> 13)], 1);
    csr_col[p] = (int)(v & 0x1FFFFu);
  }
}

// ============ SpMM (bf16 stripes, per-edge dinv weight) ============
__global__ __launch_bounds__(256) void spmm_half_kernel(
    const int* __restrict__ offsets, const int* __restrict__ csr_col,
    const float* __restrict__ dinv, const uint4* __restrict__ xb,
    uint4* __restrict__ h, int N, int hoff) {
  int wave = threadIdx.x >> 6;
  int lane = threadIdx.x & 63;
  int i = blockIdx.x * 4 + wave;
  if (i >= N) return;
  int g = lane >> 4;  // edge group 0..3
  int l = lane & 15;  // 8-feature chunk within stripe
  int beg = offsets[i], end = offsets[i + 1];

  float acc[8];
#pragma unroll
  for (int j = 0; j < 8; ++j) acc[j] = 0.f;

  int e = beg + g;
  for (; e + 12 < end; e += 16) {
    int c0 = csr_col[e], c1 = csr_col[e + 4], c2 = csr_col[e + 8], c3 = csr_col[e + 12];
    float w0 = dinv[c0], w1 = dinv[c1], w2 = dinv[c2], w3 = dinv[c3];
    uint4 v0 = xb[(size_t)c0 * 16 + l];
    uint4 v1 = xb[(size_t)c1 * 16 + l];
    uint4 v2 = xb[(size_t)c2 * 16 + l];
    uint4 v3 = xb[(size_t)c3 * 16 + l];
    acc8w(acc, v0, w0);
    acc8w(acc, v1, w1);
    acc8w(acc, v2, w2);
    acc8w(acc, v3, w3);
  }
  for (; e < end; e += 4) {
    int c = csr_col[e];
    float w = dinv[c];
    uint4 v = xb[(size_t)c * 16 + l];
    acc8w(acc, v, w);
  }

#pragma unroll
  for (int j = 0; j < 8; ++j) {
    acc[j] += __shfl(acc[j], lane ^ 16, 64);
    acc[j] += __shfl(acc[j], lane ^ 32, 64);
  }

  if (g == 0) {
    float di = dinv[i];
    uint4 o;
    o.x = f2bf(acc[0] * di) | (f2bf(acc[1] * di) << 16);
    o.y = f2bf(acc[2] * di) | (f2bf(acc[3] * di) << 16);
    o.z = f2bf(acc[4] * di) | (f2bf(acc[5] * di) << 16);
    o.w = f2bf(acc[6] * di) | (f2bf(acc[7] * di) << 16);
    h[(size_t)i * 32 + hoff + l] = o;
  }
}

// ============ FALLBACK build (atomic) ============
__global__ void deg_rank_kernel(const int* __restrict__ row, int* __restrict__ deg,
                                unsigned short* __restrict__ rank, int E) {
  int e = blockIdx.x * blockDim.x + threadIdx.x;
  if (e < E) rank[e] = (unsigned short)atomicAdd(&deg[row[e]], 1);
}
__global__ void scan1(const int* __restrict__ deg, int* __restrict__ offsets,
                      int* __restrict__ partials, int n) {
  __shared__ int tmp[256];
  int i = blockIdx.x * 256 + threadIdx.x;
  int v = (i < n) ? deg[i] : 0;
  tmp[threadIdx.x] = v;
  __syncthreads();
  for (int off = 1; off < 256; off <<= 1) {
    int t = (threadIdx.x >= off) ? tmp[threadIdx.x - off] : 0;
    __syncthreads();
    tmp[threadIdx.x] += t;
    __syncthreads();
  }
  if (i < n) offsets[i] = tmp[threadIdx.x] - v;
  if (threadIdx.x == 255) partials[blockIdx.x] = tmp[255];
}
__global__ void scan2(int* __restrict__ partials, int nb) {
  __shared__ int tmp[512];
  int tid = threadIdx.x;
  int v = (tid < nb) ? partials[tid] : 0;
  tmp[tid] = v;
  __syncthreads();
  for (int off = 1; off < 512; off <<= 1) {
    int t = (tid >= off) ? tmp[tid - off] : 0;
    __syncthreads();
    tmp[tid] += t;
    __syncthreads();
  }
  if (tid < nb) partials[tid] = tmp[tid] - v;
}
__global__ void scan3(int* __restrict__ offsets, const int* __restrict__ partials,
                      const int* __restrict__ deg, float* __restrict__ dinv, int n, int E) {
  int i = blockIdx.x * 256 + threadIdx.x;
  if (i < n) {
    offsets[i] += partials[blockIdx.x];
    int d = deg[i];
    dinv[i] = (d > 0) ? rsqrtf((float)d) : 0.0f;
    if (i == 0) offsets[n] = E;
  }
}
__global__ void fill_kernel(const int* __restrict__ row, const int* __restrict__ col,
                            const int* __restrict__ offsets, const unsigned short* __restrict__ rank,
                            int* __restrict__ csr_col, int E) {
  int e = blockIdx.x * blockDim.x + threadIdx.x;
  if (e < E) {
    int pos = offsets[row[e]] + (int)rank[e];
    csr_col[pos] = col[e];
  }
}
__global__ void wt_kernel(const float* __restrict__ W, __hip_bfloat16* __restrict__ Wt) {
  int n = blockIdx.x, k = threadIdx.x;
  Wt[n * D + k] = __float2bfloat16(W[k * D + n]);
}
__global__ __launch_bounds__(256) void spmm_f32_kernel(
    const int* __restrict__ offsets, const int* __restrict__ csr_col,
    const float* __restrict__ dinv, const float* __restrict__ x,
    unsigned short* __restrict__ h, int N) {
  int wave = threadIdx.x >> 6;
  int lane = threadIdx.x & 63;
  int i = blockIdx.x * 4 + wave;
  if (i >= N) return;
  int beg = offsets[i], end = offsets[i + 1];
  float di = dinv[i];
  const float4* x4 = reinterpret_cast<const float4*>(x);
  float4 acc = make_float4(0.f, 0.f, 0.f, 0.f);
  for (int e = beg; e < end; ++e) {
    int c = csr_col[e];
    float w = di * dinv[c];
    float4 v = x4[(size_t)c * 64 + lane];
    acc.x += w * v.x; acc.y += w * v.y; acc.z += w * v.z; acc.w += w * v.w;
  }
  ushort4 o;
  o.x = (unsigned short)f2bf(acc.x);
  o.y = (unsigned short)f2bf(acc.y);
  o.z = (unsigned short)f2bf(acc.z);
  o.w = (unsigned short)f2bf(acc.w);
  *reinterpret_cast<ushort4*>(h + (size_t)i * D + lane * 4) = o;
}

// ============ GEMM with LDS-transpose epilogue ============
// Per wave: 16 rows x 256 cols. Accumulate via MFMA, stage tile in LDS,
// then store full 1KB rows with dwordx4 (coalesced).
#define LP 260  // padded LDS row stride (floats)
__global__ __launch_bounds__(256) void gemm_kernel(
    const __hip_bfloat16* __restrict__ h, const __hip_bfloat16* __restrict__ Wt,
    const float* __restrict__ bias, float* __restrict__ out, int M) {
  __shared__ float lds[4][16][LP];
  const int tid = threadIdx.x;
  const int wave = tid >> 6;
  const int lane = tid & 63;
  const int row0 = blockIdx.x * 64 + wave * 16;
  const int arow = row0 + (lane & 15);
  const int arow_c = (arow < M) ? arow : 0;
  const int kgrp = (lane >> 4) * 8;  // 0,8,16,24
  const int ncol = lane & 15;
  const int rgrp = (lane >> 4) * 4;  // accumulator row group

  const short* hp = reinterpret_cast<const short*>(h);
  const short* wtp = reinterpret_cast<const short*>(Wt);

  bf16x8 a[8];
#pragma unroll
  for (int kk = 0; kk < 8; ++kk)
    a[kk] = *reinterpret_cast<const bf16x8*>(hp + (size_t)arow_c * D + kk * 32 + kgrp);

#pragma unroll
  for (int nt = 0; nt < 16; ++nt) {
    f32x4 acc = {0.f, 0.f, 0.f, 0.f};
#pragma unroll
    for (int kk = 0; kk < 8; ++kk) {
      bf16x8 bfrag = *reinterpret_cast<const bf16x8*>(wtp + (size_t)(nt * 16 + ncol) * D + kk * 32 + kgrp);
      acc = __builtin_amdgcn_mfma_f32_16x16x32_bf16(a[kk], bfrag, acc, 0, 0, 0);
    }
#pragma unroll
    for (int r = 0; r < 4; ++r) lds[wave][rgrp + r][nt * 16 + ncol] = acc[r];
  }

  // wave-private LDS region: wave-synchronous, no barrier needed
  float4 bv = reinterpret_cast<const float4*>(bias)[lane];
#pragma unroll
  for (int j = 0; j < 16; ++j) {
    int grow = row0 + j;
    if (grow < M) {
      const float4* lp = reinterpret_cast<const float4*>(&lds[wave][j][0]);
      float4 v = lp[lane];
      v.x += bv.x; v.y += bv.y; v.z += bv.z; v.w += bv.w;
      v.x = (v.x >= 0.f) ? v.x : 0.2f * v.x;
      v.y = (v.y >= 0.f) ? v.y : 0.2f * v.y;
      v.z = (v.z >= 0.f) ? v.z : 0.2f * v.z;
      v.w = (v.w >= 0.f) ? v.w : 0.2f * v.w;
      reinterpret_cast<float4*>(out + (size_t)grow * D)[lane] = v;
    }
  }
}

extern "C" void kernel_launch(void* const* d_in, const int* in_sizes, int n_in,
                              void* d_out, int out_size, void* d_ws, size_t ws_size,
                              hipStream_t stream) {
  const float* x = (const float*)d_in[0];
  const int* ei = (const int*)d_in[1];
  const float* W = (const float*)d_in[2];
  const float* b = (const float*)d_in[3];
  float* out = (float*)d_out;

  const int N = in_sizes[0] / D;
  const int E = in_sizes[1] / 2;
  const int* row = ei;
  const int* col = ei + E;

  char* ws = (char*)d_ws;
  size_t off = 0;
  auto alloc = [&](size_t bytes) -> void* {
    void* p = ws + off;
    off += (bytes + 255) & ~(size_t)255;
    return p;
  };
  auto align256 = [](size_t v) { return (v + 255) & ~(size_t)255; };

  int* offsets = (int*)alloc((size_t)(N + 1) * 4);
  float* dinv = (float*)alloc((size_t)N * 4);
  int* csr_col = (int*)alloc((size_t)E * 4);
  char* hreg = (char*)alloc((size_t)N * D * 2);  // h; early phase hosts sorted/counts/bases
  __hip_bfloat16* Wt = (__hip_bfloat16*)alloc((size_t)D * D * 2);
  size_t tail_off = off;  // union: xb (fast) | deg+partials+rank (fallback)

  const int NB = (N + 63) >> 6;
  const int ncb = (N + 8191) >> 13;
  const int nblk = (E + CH - 1) / CH;
  const int total8 = N * D / 8;
  const int convb = (total8 + 255) / 256;

  size_t s_sorted = 0;
  size_t s_counts = s_sorted + align256((size_t)E * 4);
  size_t s_base = s_counts + align256((size_t)nblk * NB * 4);
  size_t s_total = s_base + align256((size_t)(NB + 1) * 4);
  size_t h_need = s_total + (size_t)NB * 4;

  size_t fast_need = tail_off + align256((size_t)N * D * 2);
  bool use_fast = (N <= 131072) && (NB <= 2048) && (ncb <= 16) &&
                  (h_need <= (size_t)N * D * 2) && (fast_need <= ws_size);

  unsigned short* h = (unsigned short*)hreg;

  if (use_fast) {
    unsigned int* sorted = (unsigned int*)(hreg + s_sorted);
    int* counts = (int*)(hreg + s_counts);
    int* bucket_base = (int*)(hreg + s_base);
    int* total = (int*)(hreg + s_total);
    uint4* xb0 = (uint4*)(ws + tail_off);
    uint4* xb1 = xb0 + (size_t)N * 16;

    fused_prep_kernel<<<nblk + convb + D, 256, 0, stream>>>(
        row, x, W, xb0, xb1, Wt, counts, E, NB, nblk, total8, convb);
    colscan_kernel<<<(NB + 255) / 256, 256, 0, stream>>>(counts, total, NB, nblk);
    bucket_scan_kernel<<<1, 1024, 0, stream>>>(total, bucket_base, NB);
    scatter_kernel<<<nblk, 256, 0, stream>>>(row, col, counts, bucket_base, sorted, E, NB);
    bucket_csr_kernel<<<NB, 256, 0, stream>>>(sorted, bucket_base, offsets, dinv, csr_col,
                                              N, E, NB, ncb);
    spmm_half_kernel<<<(N + 3) / 4, 256, 0, stream>>>(offsets, csr_col, dinv, xb0, (uint4*)h, N, 0);
    spmm_half_kernel<<<(N + 3) / 4, 256, 0, stream>>>(offsets, csr_col, dinv, xb1, (uint4*)h, N, 16);
  } else {
    size_t foff = tail_off;
    int* deg = (int*)(ws + foff); foff += align256((size_t)N * 4);
    int* partials = (int*)(ws + foff); foff += align256(512 * 4);
    unsigned short* rank = (unsigned short*)(ws + foff); foff += align256((size_t)E * 2);
    (void)hipMemsetAsync(deg, 0, (size_t)N * 4, stream);
    const int eb = (E + 255) / 256;
    const int nb = (N + 255) / 256;
    deg_rank_kernel<<<eb, 256, 0, stream>>>(row, deg, rank, E);
    scan1<<<nb, 256, 0, stream>>>(deg, offsets, partials, N);
    scan2<<<1, 512, 0, stream>>>(partials, nb);
    scan3<<<nb, 256, 0, stream>>>(offsets, partials, deg, dinv, N, E);
    fill_kernel<<<eb, 256, 0, stream>>>(row, col, offsets, rank, csr_col, E);
    wt_kernel<<<D, D, 0, stream>>>(W, Wt);
    spmm_f32_kernel<<<(N + 3) / 4, 256, 0, stream>>>(offsets, csr_col, dinv, x, h, N);
  }
  gemm_kernel<<<(N + 63) / 64, 256, 0, stream>>>((const __hip_bfloat16*)h, Wt, b, out, N);
}

// Round 7
// 445.075 us; speedup vs baseline: 1.1644x; 1.1644x over previous
//
#include <hip/hip_runtime.h>
#include <hip/hip_bf16.h>

#define D 256
#define CH 8192  // edges per count/scatter block

typedef __attribute__((ext_vector_type(8))) short bf16x8;
typedef __attribute__((ext_vector_type(4))) float f32x4;

static __device__ __forceinline__ unsigned int f2bf(float f) {
  __hip_bfloat16 b = __float2bfloat16(f);
  return (unsigned int)*reinterpret_cast<unsigned short*>(&b);
}
static __device__ __forceinline__ float u2f(unsigned int u) {
  return __uint_as_float(u);
}

static __device__ __forceinline__ void acc8w(float* acc, uint4 v, float wt) {
  acc[0] += wt * u2f(v.x << 16);
  acc[1] += wt * u2f(v.x & 0xffff0000u);
  acc[2] += wt * u2f(v.y << 16);
  acc[3] += wt * u2f(v.y & 0xffff0000u);
  acc[4] += wt * u2f(v.z << 16);
  acc[5] += wt * u2f(v.z & 0xffff0000u);
  acc[6] += wt * u2f(v.w << 16);
  acc[7] += wt * u2f(v.w & 0xffff0000u);
}

// ============ FAST BUILD: deterministic counting-sort CSR ============

__global__ __launch_bounds__(256) void fused_prep_kernel(
    const int* __restrict__ row, const float* __restrict__ x, const float* __restrict__ W,
    uint4* __restrict__ xb0, uint4* __restrict__ xb1, __hip_bfloat16* __restrict__ Wt,
    int* __restrict__ counts, int E, int NB, int nblk, int total8, int convb) {
  __shared__ int hist[2048];
  int bid = blockIdx.x, tid = threadIdx.x;
  if (bid < nblk) {
    for (int t = tid; t < NB; t += 256) hist[t] = 0;
    __syncthreads();
    int e0 = bid * CH, e1 = min(E, e0 + CH);
    for (int e = e0 + tid; e < e1; e += 256) atomicAdd(&hist[row[e] >> 6], 1);
    __syncthreads();
    for (int t = tid; t < NB; t += 256) counts[(size_t)bid * NB + t] = hist[t];
  } else if (bid < nblk + convb) {
    int idx = (bid - nblk) * 256 + tid;
    if (idx < total8) {
      int j = idx >> 5, k8 = idx & 31;
      const float4* x4 = reinterpret_cast<const float4*>(x);
      float4 a = x4[(size_t)idx * 2], bb = x4[(size_t)idx * 2 + 1];
      uint4 o;
      o.x = f2bf(a.x) | (f2bf(a.y) << 16);
      o.y = f2bf(a.z) | (f2bf(a.w) << 16);
      o.z = f2bf(bb.x) | (f2bf(bb.y) << 16);
      o.w = f2bf(bb.z) | (f2bf(bb.w) << 16);
      uint4* dst = (k8 < 16) ? xb0 : xb1;
      dst[(size_t)j * 16 + (k8 & 15)] = o;
    }
  } else {
    int n = bid - nblk - convb;  // 0..D-1
    Wt[n * D + tid] = __float2bfloat16(W[tid * D + n]);
  }
}

__global__ void colscan_kernel(int* counts, int* total, int NB, int nblk) {
  int t = blockIdx.x * 256 + threadIdx.x;
  if (t >= NB) return;
  int run = 0;
#pragma unroll 4
  for (int blk = 0; blk < nblk; ++blk) {
    size_t idx = (size_t)blk * NB + t;
    int c = counts[idx];
    counts[idx] = run;
    run += c;
  }
  total[t] = run;
}

__global__ void bucket_scan_kernel(const int* __restrict__ total, int* __restrict__ bucket_base,
                                   int NB) {
  __shared__ int a[2048], b2[2048];
  int t = threadIdx.x;  // 1024 threads
  for (int k = 0; k < 2; ++k) {
    int i = t + k * 1024;
    a[i] = (i < NB) ? total[i] : 0;
  }
  __syncthreads();
  int* cur = a;
  int* nxt = b2;
  for (int off = 1; off < 2048; off <<= 1) {
    for (int k = 0; k < 2; ++k) {
      int i = t + k * 1024;
      int v = cur[i];
      if (i >= off) v += cur[i - off];
      nxt[i] = v;
    }
    __syncthreads();
    int* tmp = cur; cur = nxt; nxt = tmp;
  }
  if (t == 0) bucket_base[0] = 0;
  for (int k = 0; k < 2; ++k) {
    int i = t + k * 1024;
    if (i < NB) bucket_base[i + 1] = cur[i];
  }
}

__global__ __launch_bounds__(256) void scatter_kernel(
    const int* __restrict__ row, const int* __restrict__ col, const int* __restrict__ counts,
    const int* __restrict__ bucket_base, unsigned int* __restrict__ sorted, int E, int NB) {
  __shared__ int base[2048];
  __shared__ int cur[2048];
  int bid = blockIdx.x, tid = threadIdx.x;
  for (int t = tid; t < NB; t += 256) {
    base[t] = bucket_base[t] + counts[(size_t)bid * NB + t];
    cur[t] = 0;
  }
  __syncthreads();
  int e0 = bid * CH, e1 = min(E, e0 + CH);
  for (int e = e0 + tid; e < e1; e += 256) {
    int r = row[e], c = col[e];
    int b = r >> 6;
    int p = base[b] + atomicAdd(&cur[b], 1);
    sorted[p] = ((unsigned int)(r & 63) << 17) | (unsigned int)c;
  }
}

__global__ __launch_bounds__(256) void bucket_csr_kernel(
    const unsigned int* __restrict__ sorted, const int* __restrict__ bucket_base,
    int* __restrict__ offsets, float* __restrict__ dinv, int* __restrict__ csr_col,
    int N, int E, int NB, int ncb) {
  __shared__ int cnt[1024];
  int b = blockIdx.x, tid = threadIdx.x;
  int lo = bucket_base[b], hi = bucket_base[b + 1];
  int slots = 64 * ncb;
  for (int t = tid; t < slots; t += 256) cnt[t] = 0;
  __syncthreads();
  for (int e = lo + tid; e < hi; e += 256) {
    unsigned int v = sorted[e];
    atomicAdd(&cnt[(v >> 17) * ncb + ((v & 0x1FFFFu) >> 13)], 1);
  }
  __syncthreads();
  if (tid == 0) {
    int run = 0;
    for (int i2 = 0; i2 < slots; ++i2) {
      int t2 = cnt[i2];
      cnt[i2] = run;
      run += t2;
    }
  }
  __syncthreads();
  if (tid < 64) {
    int gr = b * 64 + tid;
    if (gr < N) {
      int start = cnt[tid * ncb];
      int nxt = (tid == 63) ? (hi - lo) : cnt[(tid + 1) * ncb];
      int dg = nxt - start;
      offsets[gr] = lo + start;
      dinv[gr] = (dg > 0) ? rsqrtf((float)dg) : 0.f;
    }
  }
  if (b == NB - 1 && tid == 0) offsets[N] = E;
  __syncthreads();
  for (int e = lo + tid; e < hi; e += 256) {
    unsigned int v = sorted[e];
    int p = lo + atomicAdd(&cnt[(v >> 17) * ncb + ((v & 0x1FFFFu) >> 13)], 1);
    csr_col[p] = (int)(v & 0x1FFFFu);
  }
}

// ============ SpMM (bf16 stripes, per-edge dinv weight) ============
__global__ __launch_bounds__(256) void spmm_half_kernel(
    const int* __restrict__ offsets, const int* __restrict__ csr_col,
    const float* __restrict__ dinv, const uint4* __restrict__ xb,
    uint4* __restrict__ h, int N, int hoff) {
  int wave = threadIdx.x >> 6;
  int lane = threadIdx.x & 63;
  int i = blockIdx.x * 4 + wave;
  if (i >= N) return;
  int g = lane >> 4;  // edge group 0..3
  int l = lane & 15;  // 8-feature chunk within stripe
  int beg = offsets[i], end = offsets[i + 1];

  float acc[8];
#pragma unroll
  for (int j = 0; j < 8; ++j) acc[j] = 0.f;

  int e = beg + g;
  for (; e + 12 < end; e += 16) {
    int c0 = csr_col[e], c1 = csr_col[e + 4], c2 = csr_col[e + 8], c3 = csr_col[e + 12];
    float w0 = dinv[c0], w1 = dinv[c1], w2 = dinv[c2], w3 = dinv[c3];
    uint4 v0 = xb[(size_t)c0 * 16 + l];
    uint4 v1 = xb[(size_t)c1 * 16 + l];
    uint4 v2 = xb[(size_t)c2 * 16 + l];
    uint4 v3 = xb[(size_t)c3 * 16 + l];
    acc8w(acc, v0, w0);
    acc8w(acc, v1, w1);
    acc8w(acc, v2, w2);
    acc8w(acc, v3, w3);
  }
  for (; e < end; e += 4) {
    int c = csr_col[e];
    float w = dinv[c];
    uint4 v = xb[(size_t)c * 16 + l];
    acc8w(acc, v, w);
  }

#pragma unroll
  for (int j = 0; j < 8; ++j) {
    acc[j] += __shfl(acc[j], lane ^ 16, 64);
    acc[j] += __shfl(acc[j], lane ^ 32, 64);
  }

  if (g == 0) {
    float di = dinv[i];
    uint4 o;
    o.x = f2bf(acc[0] * di) | (f2bf(acc[1] * di) << 16);
    o.y = f2bf(acc[2] * di) | (f2bf(acc[3] * di) << 16);
    o.z = f2bf(acc[4] * di) | (f2bf(acc[5] * di) << 16);
    o.w = f2bf(acc[6] * di) | (f2bf(acc[7] * di) << 16);
    h[(size_t)i * 32 + hoff + l] = o;
  }
}

// ============ FALLBACK build (atomic) ============
__global__ void deg_rank_kernel(const int* __restrict__ row, int* __restrict__ deg,
                                unsigned short* __restrict__ rank, int E) {
  int e = blockIdx.x * blockDim.x + threadIdx.x;
  if (e < E) rank[e] = (unsigned short)atomicAdd(&deg[row[e]], 1);
}
__global__ void scan1(const int* __restrict__ deg, int* __restrict__ offsets,
                      int* __restrict__ partials, int n) {
  __shared__ int tmp[256];
  int i = blockIdx.x * 256 + threadIdx.x;
  int v = (i < n) ? deg[i] : 0;
  tmp[threadIdx.x] = v;
  __syncthreads();
  for (int off = 1; off < 256; off <<= 1) {
    int t = (threadIdx.x >= off) ? tmp[threadIdx.x - off] : 0;
    __syncthreads();
    tmp[threadIdx.x] += t;
    __syncthreads();
  }
  if (i < n) offsets[i] = tmp[threadIdx.x] - v;
  if (threadIdx.x == 255) partials[blockIdx.x] = tmp[255];
}
__global__ void scan2(int* __restrict__ partials, int nb) {
  __shared__ int tmp[512];
  int tid = threadIdx.x;
  int v = (tid < nb) ? partials[tid] : 0;
  tmp[tid] = v;
  __syncthreads();
  for (int off = 1; off < 512; off <<= 1) {
    int t = (tid >= off) ? tmp[tid - off] : 0;
    __syncthreads();
    tmp[tid] += t;
    __syncthreads();
  }
  if (tid < nb) partials[tid] = tmp[tid] - v;
}
__global__ void scan3(int* __restrict__ offsets, const int* __restrict__ partials,
                      const int* __restrict__ deg, float* __restrict__ dinv, int n, int E) {
  int i = blockIdx.x * 256 + threadIdx.x;
  if (i < n) {
    offsets[i] += partials[blockIdx.x];
    int d = deg[i];
    dinv[i] = (d > 0) ? rsqrtf((float)d) : 0.0f;
    if (i == 0) offsets[n] = E;
  }
}
__global__ void fill_kernel(const int* __restrict__ row, const int* __restrict__ col,
                            const int* __restrict__ offsets, const unsigned short* __restrict__ rank,
                            int* __restrict__ csr_col, int E) {
  int e = blockIdx.x * blockDim.x + threadIdx.x;
  if (e < E) {
    int pos = offsets[row[e]] + (int)rank[e];
    csr_col[pos] = col[e];
  }
}
__global__ void wt_kernel(const float* __restrict__ W, __hip_bfloat16* __restrict__ Wt) {
  int n = blockIdx.x, k = threadIdx.x;
  Wt[n * D + k] = __float2bfloat16(W[k * D + n]);
}
__global__ __launch_bounds__(256) void spmm_f32_kernel(
    const int* __restrict__ offsets, const int* __restrict__ csr_col,
    const float* __restrict__ dinv, const float* __restrict__ x,
    unsigned short* __restrict__ h, int N) {
  int wave = threadIdx.x >> 6;
  int lane = threadIdx.x & 63;
  int i = blockIdx.x * 4 + wave;
  if (i >= N) return;
  int beg = offsets[i], end = offsets[i + 1];
  float di = dinv[i];
  const float4* x4 = reinterpret_cast<const float4*>(x);
  float4 acc = make_float4(0.f, 0.f, 0.f, 0.f);
  for (int e = beg; e < end; ++e) {
    int c = csr_col[e];
    float w = di * dinv[c];
    float4 v = x4[(size_t)c * 64 + lane];
    acc.x += w * v.x; acc.y += w * v.y; acc.z += w * v.z; acc.w += w * v.w;
  }
  ushort4 o;
  o.x = (unsigned short)f2bf(acc.x);
  o.y = (unsigned short)f2bf(acc.y);
  o.z = (unsigned short)f2bf(acc.z);
  o.w = (unsigned short)f2bf(acc.w);
  *reinterpret_cast<ushort4*>(h + (size_t)i * D + lane * 4) = o;
}

// ============ GEMM v3: W register-resident, grid-stride over 16-row tiles ============
// Each wave owns a 64-col slice of Wt (128 VGPRs, loaded once). A double-buffered.
__global__ __launch_bounds__(256, 2) void gemm_kernel(
    const __hip_bfloat16* __restrict__ h, const __hip_bfloat16* __restrict__ Wt,
    const float* __restrict__ bias, float* __restrict__ out, int M, int ntiles) {
  const int tid = threadIdx.x;
  const int wave = tid >> 6;   // col-slice [wave*64, wave*64+64)
  const int lane = tid & 63;
  const int ncol = lane & 15;
  const int kgrp = (lane >> 4) * 8;
  const int rgrp = (lane >> 4) * 4;
  const int col0 = wave * 64;

  const short* hp = reinterpret_cast<const short*>(h);
  const short* wtp = reinterpret_cast<const short*>(Wt);

  // --- load this wave's W slice into registers (once) ---
  bf16x8 breg[4][8];
#pragma unroll
  for (int nt = 0; nt < 4; ++nt)
#pragma unroll
    for (int kk = 0; kk < 8; ++kk)
      breg[nt][kk] =
          *reinterpret_cast<const bf16x8*>(wtp + (size_t)(col0 + nt * 16 + ncol) * D + kk * 32 + kgrp);

  float bv[4];
#pragma unroll
  for (int nt = 0; nt < 4; ++nt) bv[nt] = bias[col0 + nt * 16 + ncol];

  const int stride = gridDim.x;
  int t = blockIdx.x;
  if (t >= ntiles) return;

  // prologue: load A for first tile
  bf16x8 a[8];
  {
    int arow = t * 16 + (lane & 15);
    int arow_c = (arow < M) ? arow : 0;
#pragma unroll
    for (int kk = 0; kk < 8; ++kk)
      a[kk] = *reinterpret_cast<const bf16x8*>(hp + (size_t)arow_c * D + kk * 32 + kgrp);
  }

  for (; t < ntiles; t += stride) {
    int tn = t + stride;
    bf16x8 an[8];
    if (tn < ntiles) {
      int arow = tn * 16 + (lane & 15);
      int arow_c = (arow < M) ? arow : 0;
#pragma unroll
      for (int kk = 0; kk < 8; ++kk)
        an[kk] = *reinterpret_cast<const bf16x8*>(hp + (size_t)arow_c * D + kk * 32 + kgrp);
    }

    f32x4 acc[4];
#pragma unroll
    for (int nt = 0; nt < 4; ++nt) acc[nt] = (f32x4){0.f, 0.f, 0.f, 0.f};
#pragma unroll
    for (int nt = 0; nt < 4; ++nt)
#pragma unroll
      for (int kk = 0; kk < 8; ++kk)
        acc[nt] = __builtin_amdgcn_mfma_f32_16x16x32_bf16(a[kk], breg[nt][kk], acc[nt], 0, 0, 0);

    int row0 = t * 16;
#pragma unroll
    for (int nt = 0; nt < 4; ++nt) {
      int col = col0 + nt * 16 + ncol;
#pragma unroll
      for (int r = 0; r < 4; ++r) {
        int row = row0 + rgrp + r;
        if (row < M) {
          float v = acc[nt][r] + bv[nt];
          out[(size_t)row * D + col] = (v >= 0.f) ? v : 0.2f * v;
        }
      }
    }

#pragma unroll
    for (int kk = 0; kk < 8; ++kk) a[kk] = an[kk];
  }
}

extern "C" void kernel_launch(void* const* d_in, const int* in_sizes, int n_in,
                              void* d_out, int out_size, void* d_ws, size_t ws_size,
                              hipStream_t stream) {
  const float* x = (const float*)d_in[0];
  const int* ei = (const int*)d_in[1];
  const float* W = (const float*)d_in[2];
  const float* b = (const float*)d_in[3];
  float* out = (float*)d_out;

  const int N = in_sizes[0] / D;
  const int E = in_sizes[1] / 2;
  const int* row = ei;
  const int* col = ei + E;

  char* ws = (char*)d_ws;
  size_t off = 0;
  auto alloc = [&](size_t bytes) -> void* {
    void* p = ws + off;
    off += (bytes + 255) & ~(size_t)255;
    return p;
  };
  auto align256 = [](size_t v) { return (v + 255) & ~(size_t)255; };

  int* offsets = (int*)alloc((size_t)(N + 1) * 4);
  float* dinv = (float*)alloc((size_t)N * 4);
  int* csr_col = (int*)alloc((size_t)E * 4);
  char* hreg = (char*)alloc((size_t)N * D * 2);  // h; early phase hosts sorted/counts/bases
  __hip_bfloat16* Wt = (__hip_bfloat16*)alloc((size_t)D * D * 2);
  size_t tail_off = off;  // union: xb (fast) | deg+partials+rank (fallback)

  const int NB = (N + 63) >> 6;
  const int ncb = (N + 8191) >> 13;
  const int nblk = (E + CH - 1) / CH;
  const int total8 = N * D / 8;
  const int convb = (total8 + 255) / 256;

  size_t s_sorted = 0;
  size_t s_counts = s_sorted + align256((size_t)E * 4);
  size_t s_base = s_counts + align256((size_t)nblk * NB * 4);
  size_t s_total = s_base + align256((size_t)(NB + 1) * 4);
  size_t h_need = s_total + (size_t)NB * 4;

  size_t fast_need = tail_off + align256((size_t)N * D * 2);
  bool use_fast = (N <= 131072) && (NB <= 2048) && (ncb <= 16) &&
                  (h_need <= (size_t)N * D * 2) && (fast_need <= ws_size);

  unsigned short* h = (unsigned short*)hreg;

  if (use_fast) {
    unsigned int* sorted = (unsigned int*)(hreg + s_sorted);
    int* counts = (int*)(hreg + s_counts);
    int* bucket_base = (int*)(hreg + s_base);
    int* total = (int*)(hreg + s_total);
    uint4* xb0 = (uint4*)(ws + tail_off);
    uint4* xb1 = xb0 + (size_t)N * 16;

    fused_prep_kernel<<<nblk + convb + D, 256, 0, stream>>>(
        row, x, W, xb0, xb1, Wt, counts, E, NB, nblk, total8, convb);
    colscan_kernel<<<(NB + 255) / 256, 256, 0, stream>>>(counts, total, NB, nblk);
    bucket_scan_kernel<<<1, 1024, 0, stream>>>(total, bucket_base, NB);
    scatter_kernel<<<nblk, 256, 0, stream>>>(row, col, counts, bucket_base, sorted, E, NB);
    bucket_csr_kernel<<<NB, 256, 0, stream>>>(sorted, bucket_base, offsets, dinv, csr_col,
                                              N, E, NB, ncb);
    spmm_half_kernel<<<(N + 3) / 4, 256, 0, stream>>>(offsets, csr_col, dinv, xb0, (uint4*)h, N, 0);
    spmm_half_kernel<<<(N + 3) / 4, 256, 0, stream>>>(offsets, csr_col, dinv, xb1, (uint4*)h, N, 16);
  } else {
    size_t foff = tail_off;
    int* deg = (int*)(ws + foff); foff += align256((size_t)N * 4);
    int* partials = (int*)(ws + foff); foff += align256(512 * 4);
    unsigned short* rank = (unsigned short*)(ws + foff); foff += align256((size_t)E * 2);
    (void)hipMemsetAsync(deg, 0, (size_t)N * 4, stream);
    const int eb = (E + 255) / 256;
    const int nb = (N + 255) / 256;
    deg_rank_kernel<<<eb, 256, 0, stream>>>(row, deg, rank, E);
    scan1<<<nb, 256, 0, stream>>>(deg, offsets, partials, N);
    scan2<<<1, 512, 0, stream>>>(partials, nb);
    scan3<<<nb, 256, 0, stream>>>(offsets, partials, deg, dinv, N, E);
    fill_kernel<<<eb, 256, 0, stream>>>(row, col, offsets, rank, csr_col, E);
    wt_kernel<<<D, D, 0, stream>>>(W, Wt);
    spmm_f32_kernel<<<(N + 3) / 4, 256, 0, stream>>>(offsets, csr_col, dinv, x, h, N);
  }
  const int ntiles = (N + 15) / 16;
  int gB = ntiles < 512 ? ntiles : 512;
  gemm_kernel<<<gB, 256, 0, stream>>>((const __hip_bfloat16*)h, Wt, b, out, N, ntiles);
}

// Round 8
// 383.244 us; speedup vs baseline: 1.3523x; 1.1613x over previous
//
#include <hip/hip_runtime.h>
#include <hip/hip_bf16.h>

#define D 256
#define CH 8192     // edges per count/scatter block
#define MAXNCB 15   // max col-windows (N <= 122880)

typedef __attribute__((ext_vector_type(8))) short bf16x8;
typedef __attribute__((ext_vector_type(4))) float f32x4;

static __device__ __forceinline__ unsigned int f2bf(float f) {
  __hip_bfloat16 b = __float2bfloat16(f);
  return (unsigned int)*reinterpret_cast<unsigned short*>(&b);
}
static __device__ __forceinline__ float u2f(unsigned int u) {
  return __uint_as_float(u);
}

static __device__ __forceinline__ void acc8w(float* acc, uint4 v, float wt) {
  acc[0] += wt * u2f(v.x << 16);
  acc[1] += wt * u2f(v.x & 0xffff0000u);
  acc[2] += wt * u2f(v.y << 16);
  acc[3] += wt * u2f(v.y & 0xffff0000u);
  acc[4] += wt * u2f(v.z << 16);
  acc[5] += wt * u2f(v.z & 0xffff0000u);
  acc[6] += wt * u2f(v.w << 16);
  acc[7] += wt * u2f(v.w & 0xffff0000u);
}

// ============ FAST BUILD: two-level counting sort (1024-row coarse buckets) ============

// K1 fused: [0,nblk) coarse count | [nblk,nblk+convb) x->bf16 stripes | [+,+D) W^T
// counts layout: bucket-major counts[t * nblk + blk]
__global__ __launch_bounds__(256) void fused_prep_kernel(
    const int* __restrict__ row, const float* __restrict__ x, const float* __restrict__ W,
    uint4* __restrict__ xb0, uint4* __restrict__ xb1, __hip_bfloat16* __restrict__ Wt,
    int* __restrict__ counts, int E, int NCBK, int nblk, int total8, int convb) {
  __shared__ int hist[128];
  int bid = blockIdx.x, tid = threadIdx.x;
  if (bid < nblk) {
    if (tid < 128) hist[tid] = 0;
    __syncthreads();
    int e0 = bid * CH, e1 = min(E, e0 + CH);
    for (int e = e0 + tid; e < e1; e += 256) atomicAdd(&hist[row[e] >> 10], 1);
    __syncthreads();
    for (int t = tid; t < NCBK; t += 256) counts[(size_t)t * nblk + bid] = hist[t];
  } else if (bid < nblk + convb) {
    int idx = (bid - nblk) * 256 + tid;
    if (idx < total8) {
      int j = idx >> 5, k8 = idx & 31;
      const float4* x4 = reinterpret_cast<const float4*>(x);
      float4 a = x4[(size_t)idx * 2], bb = x4[(size_t)idx * 2 + 1];
      uint4 o;
      o.x = f2bf(a.x) | (f2bf(a.y) << 16);
      o.y = f2bf(a.z) | (f2bf(a.w) << 16);
      o.z = f2bf(bb.x) | (f2bf(bb.y) << 16);
      o.w = f2bf(bb.z) | (f2bf(bb.w) << 16);
      uint4* dst = (k8 < 16) ? xb0 : xb1;
      dst[(size_t)j * 16 + (k8 & 15)] = o;
    }
  } else {
    int n = bid - nblk - convb;  // 0..D-1
    Wt[n * D + tid] = __float2bfloat16(W[tid * D + n]);
  }
}

// K2a: per-bucket exclusive scan over its nblk entries (one block per bucket)
__global__ __launch_bounds__(256) void colscan_kernel(int* __restrict__ counts,
                                                      int* __restrict__ total, int nblk) {
  __shared__ int a[512], bb[512];
  int t = blockIdx.x, tid = threadIdx.x;
  int* base = counts + (size_t)t * nblk;
  int v0[2];
  for (int k = 0; k < 2; ++k) {
    int i = tid + k * 256;
    v0[k] = (i < nblk) ? base[i] : 0;
    a[i] = v0[k];
  }
  __syncthreads();
  int* cur = a;
  int* nxt = bb;
  for (int off = 1; off < 512; off <<= 1) {
    for (int k = 0; k < 2; ++k) {
      int i = tid + k * 256;
      int v = cur[i];
      if (i >= off) v += cur[i - off];
      nxt[i] = v;
    }
    __syncthreads();
    int* tmp = cur; cur = nxt; nxt = tmp;
  }
  for (int k = 0; k < 2; ++k) {
    int i = tid + k * 256;
    if (i < nblk) {
      base[i] = cur[i] - v0[k];  // exclusive
      if (i == nblk - 1) total[t] = cur[i];
    }
  }
}

// K2b: scan bucket totals -> bucket_base[NCBK+1]
__global__ void bucket_scan_kernel(const int* __restrict__ total, int* __restrict__ bucket_base,
                                   int NCBK) {
  __shared__ int a[256], bb[256];
  int t = threadIdx.x;
  a[t] = (t < NCBK) ? total[t] : 0;
  __syncthreads();
  int* cur = a;
  int* nxt = bb;
  for (int off = 1; off < 256; off <<= 1) {
    int v = cur[t];
    if (t >= off) v += cur[t - off];
    nxt[t] = v;
    __syncthreads();
    int* tmp = cur; cur = nxt; nxt = tmp;
  }
  if (t == 0) bucket_base[0] = 0;
  if (t < NCBK) bucket_base[t + 1] = cur[t];
}

// K3: scatter into coarse-bucket order; pack (row&1023)<<17 | col
__global__ __launch_bounds__(256) void scatter_kernel(
    const int* __restrict__ row, const int* __restrict__ col, const int* __restrict__ counts,
    const int* __restrict__ bucket_base, unsigned int* __restrict__ sorted, int E, int NCBK,
    int nblk) {
  __shared__ int base[128];
  __shared__ int cur[128];
  int bid = blockIdx.x, tid = threadIdx.x;
  for (int t = tid; t < NCBK; t += 256) {
    base[t] = bucket_base[t] + counts[(size_t)t * nblk + bid];
    cur[t] = 0;
  }
  __syncthreads();
  int e0 = bid * CH, e1 = min(E, e0 + CH);
  for (int e = e0 + tid; e < e1; e += 256) {
    int r = row[e], c = col[e];
    int b = r >> 10;
    int p = base[b] + atomicAdd(&cur[b], 1);
    sorted[p] = ((unsigned int)(r & 1023) << 17) | (unsigned int)c;
  }
}

// K4: per 1024-node bucket: LDS (node, col>>13) count + parallel scan -> offsets/dinv/csr_col
__global__ __launch_bounds__(512) void bucket_csr_kernel(
    const unsigned int* __restrict__ sorted, const int* __restrict__ bucket_base,
    int* __restrict__ offsets, float* __restrict__ dinv, int* __restrict__ csr_col,
    int N, int E, int NCBK, int ncb) {
  __shared__ int cnt[1024 * MAXNCB];
  __shared__ int auxa[512], auxb[512];
  int b = blockIdx.x, tid = threadIdx.x;
  int lo = bucket_base[b], hi = bucket_base[b + 1];
  int slots = 1024 * ncb;
  for (int t = tid; t < slots; t += 512) cnt[t] = 0;
  __syncthreads();
  for (int e = lo + tid; e < hi; e += 512) {
    unsigned int v = sorted[e];
    atomicAdd(&cnt[(v >> 17) * ncb + ((v & 0x1FFFFu) >> 13)], 1);
  }
  __syncthreads();
  // parallel exclusive scan of cnt[0..slots)
  int per = (slots + 511) / 512;
  int i0 = tid * per;
  int run = 0;
  for (int k = 0; k < per; ++k) {
    int i = i0 + k;
    if (i < slots) {
      int c = cnt[i];
      cnt[i] = run;
      run += c;
    }
  }
  auxa[tid] = run;
  __syncthreads();
  int* cur = auxa;
  int* nxt = auxb;
  for (int off = 1; off < 512; off <<= 1) {
    int v = cur[tid];
    if (tid >= off) v += cur[tid - off];
    nxt[tid] = v;
    __syncthreads();
    int* tmp = cur; cur = nxt; nxt = tmp;
  }
  int add = (tid > 0) ? cur[tid - 1] : 0;
  for (int k = 0; k < per; ++k) {
    int i = i0 + k;
    if (i < slots) cnt[i] += add;
  }
  __syncthreads();
  // offsets + dinv
  for (int nl = tid; nl < 1024; nl += 512) {
    int gr = b * 1024 + nl;
    if (gr < N) {
      int start = cnt[nl * ncb];
      int nxt_s = (nl == 1023) ? (hi - lo) : cnt[(nl + 1) * ncb];
      int dg = nxt_s - start;
      offsets[gr] = lo + start;
      dinv[gr] = (dg > 0) ? rsqrtf((float)dg) : 0.f;
    }
  }
  if (b == NCBK - 1 && tid == 0) offsets[N] = E;
  __syncthreads();
  for (int e = lo + tid; e < hi; e += 512) {
    unsigned int v = sorted[e];
    int p = lo + atomicAdd(&cnt[(v >> 17) * ncb + ((v & 0x1FFFFu) >> 13)], 1);
    csr_col[p] = (int)(v & 0x1FFFFu);
  }
}

// ============ SpMM (bf16 stripes, per-edge dinv weight) ============
__global__ __launch_bounds__(256) void spmm_half_kernel(
    const int* __restrict__ offsets, const int* __restrict__ csr_col,
    const float* __restrict__ dinv, const uint4* __restrict__ xb,
    uint4* __restrict__ h, int N, int hoff) {
  int wave = threadIdx.x >> 6;
  int lane = threadIdx.x & 63;
  int i = blockIdx.x * 4 + wave;
  if (i >= N) return;
  int g = lane >> 4;  // edge group 0..3
  int l = lane & 15;  // 8-feature chunk within stripe
  int beg = offsets[i], end = offsets[i + 1];

  float acc[8];
#pragma unroll
  for (int j = 0; j < 8; ++j) acc[j] = 0.f;

  int e = beg + g;
  for (; e + 12 < end; e += 16) {
    int c0 = csr_col[e], c1 = csr_col[e + 4], c2 = csr_col[e + 8], c3 = csr_col[e + 12];
    float w0 = dinv[c0], w1 = dinv[c1], w2 = dinv[c2], w3 = dinv[c3];
    uint4 v0 = xb[(size_t)c0 * 16 + l];
    uint4 v1 = xb[(size_t)c1 * 16 + l];
    uint4 v2 = xb[(size_t)c2 * 16 + l];
    uint4 v3 = xb[(size_t)c3 * 16 + l];
    acc8w(acc, v0, w0);
    acc8w(acc, v1, w1);
    acc8w(acc, v2, w2);
    acc8w(acc, v3, w3);
  }
  for (; e < end; e += 4) {
    int c = csr_col[e];
    float w = dinv[c];
    uint4 v = xb[(size_t)c * 16 + l];
    acc8w(acc, v, w);
  }

#pragma unroll
  for (int j = 0; j < 8; ++j) {
    acc[j] += __shfl(acc[j], lane ^ 16, 64);
    acc[j] += __shfl(acc[j], lane ^ 32, 64);
  }

  if (g == 0) {
    float di = dinv[i];
    uint4 o;
    o.x = f2bf(acc[0] * di) | (f2bf(acc[1] * di) << 16);
    o.y = f2bf(acc[2] * di) | (f2bf(acc[3] * di) << 16);
    o.z = f2bf(acc[4] * di) | (f2bf(acc[5] * di) << 16);
    o.w = f2bf(acc[6] * di) | (f2bf(acc[7] * di) << 16);
    h[(size_t)i * 32 + hoff + l] = o;
  }
}

// ============ FALLBACK build (atomic) ============
__global__ void deg_rank_kernel(const int* __restrict__ row, int* __restrict__ deg,
                                unsigned short* __restrict__ rank, int E) {
  int e = blockIdx.x * blockDim.x + threadIdx.x;
  if (e < E) rank[e] = (unsigned short)atomicAdd(&deg[row[e]], 1);
}
__global__ void fscan1(const int* __restrict__ deg, int* __restrict__ offsets,
                       int* __restrict__ partials, int n) {
  __shared__ int tmp[256];
  int i = blockIdx.x * 256 + threadIdx.x;
  int v = (i < n) ? deg[i] : 0;
  tmp[threadIdx.x] = v;
  __syncthreads();
  for (int off = 1; off < 256; off <<= 1) {
    int t = (threadIdx.x >= off) ? tmp[threadIdx.x - off] : 0;
    __syncthreads();
    tmp[threadIdx.x] += t;
    __syncthreads();
  }
  if (i < n) offsets[i] = tmp[threadIdx.x] - v;
  if (threadIdx.x == 255) partials[blockIdx.x] = tmp[255];
}
__global__ void fscan2(int* __restrict__ partials, int nb) {
  __shared__ int tmp[512];
  int tid = threadIdx.x;
  int v = (tid < nb) ? partials[tid] : 0;
  tmp[tid] = v;
  __syncthreads();
  for (int off = 1; off < 512; off <<= 1) {
    int t = (tid >= off) ? tmp[tid - off] : 0;
    __syncthreads();
    tmp[tid] += t;
    __syncthreads();
  }
  if (tid < nb) partials[tid] = tmp[tid] - v;
}
__global__ void fscan3(int* __restrict__ offsets, const int* __restrict__ partials,
                       const int* __restrict__ deg, float* __restrict__ dinv, int n, int E) {
  int i = blockIdx.x * 256 + threadIdx.x;
  if (i < n) {
    offsets[i] += partials[blockIdx.x];
    int d = deg[i];
    dinv[i] = (d > 0) ? rsqrtf((float)d) : 0.0f;
    if (i == 0) offsets[n] = E;
  }
}
__global__ void fill_kernel(const int* __restrict__ row, const int* __restrict__ col,
                            const int* __restrict__ offsets, const unsigned short* __restrict__ rank,
                            int* __restrict__ csr_col, int E) {
  int e = blockIdx.x * blockDim.x + threadIdx.x;
  if (e < E) {
    int pos = offsets[row[e]] + (int)rank[e];
    csr_col[pos] = col[e];
  }
}
__global__ void wt_kernel(const float* __restrict__ W, __hip_bfloat16* __restrict__ Wt) {
  int n = blockIdx.x, k = threadIdx.x;
  Wt[n * D + k] = __float2bfloat16(W[k * D + n]);
}
__global__ __launch_bounds__(256) void spmm_f32_kernel(
    const int* __restrict__ offsets, const int* __restrict__ csr_col,
    const float* __restrict__ dinv, const float* __restrict__ x,
    unsigned short* __restrict__ h, int N) {
  int wave = threadIdx.x >> 6;
  int lane = threadIdx.x & 63;
  int i = blockIdx.x * 4 + wave;
  if (i >= N) return;
  int beg = offsets[i], end = offsets[i + 1];
  float di = dinv[i];
  const float4* x4 = reinterpret_cast<const float4*>(x);
  float4 acc = make_float4(0.f, 0.f, 0.f, 0.f);
  for (int e = beg; e < end; ++e) {
    int c = csr_col[e];
    float w = di * dinv[c];
    float4 v = x4[(size_t)c * 64 + lane];
    acc.x += w * v.x; acc.y += w * v.y; acc.z += w * v.z; acc.w += w * v.w;
  }
  ushort4 o;
  o.x = (unsigned short)f2bf(acc.x);
  o.y = (unsigned short)f2bf(acc.y);
  o.z = (unsigned short)f2bf(acc.z);
  o.w = (unsigned short)f2bf(acc.w);
  *reinterpret_cast<ushort4*>(h + (size_t)i * D + lane * 4) = o;
}

// ============ GEMM: W register-resident, grid-stride over 16-row tiles ============
__global__ __launch_bounds__(256, 2) void gemm_kernel(
    const __hip_bfloat16* __restrict__ h, const __hip_bfloat16* __restrict__ Wt,
    const float* __restrict__ bias, float* __restrict__ out, int M, int ntiles) {
  const int tid = threadIdx.x;
  const int wave = tid >> 6;   // col-slice [wave*64, wave*64+64)
  const int lane = tid & 63;
  const int ncol = lane & 15;
  const int kgrp = (lane >> 4) * 8;
  const int rgrp = (lane >> 4) * 4;
  const int col0 = wave * 64;

  const short* hp = reinterpret_cast<const short*>(h);
  const short* wtp = reinterpret_cast<const short*>(Wt);

  bf16x8 breg[4][8];
#pragma unroll
  for (int nt = 0; nt < 4; ++nt)
#pragma unroll
    for (int kk = 0; kk < 8; ++kk)
      breg[nt][kk] =
          *reinterpret_cast<const bf16x8*>(wtp + (size_t)(col0 + nt * 16 + ncol) * D + kk * 32 + kgrp);

  float bv[4];
#pragma unroll
  for (int nt = 0; nt < 4; ++nt) bv[nt] = bias[col0 + nt * 16 + ncol];

  const int stride = gridDim.x;
  int t = blockIdx.x;
  if (t >= ntiles) return;

  bf16x8 a[8];
  {
    int arow = t * 16 + (lane & 15);
    int arow_c = (arow < M) ? arow : 0;
#pragma unroll
    for (int kk = 0; kk < 8; ++kk)
      a[kk] = *reinterpret_cast<const bf16x8*>(hp + (size_t)arow_c * D + kk * 32 + kgrp);
  }

  for (; t < ntiles; t += stride) {
    int tn = t + stride;
    bf16x8 an[8];
    if (tn < ntiles) {
      int arow = tn * 16 + (lane & 15);
      int arow_c = (arow < M) ? arow : 0;
#pragma unroll
      for (int kk = 0; kk < 8; ++kk)
        an[kk] = *reinterpret_cast<const bf16x8*>(hp + (size_t)arow_c * D + kk * 32 + kgrp);
    }

    f32x4 acc[4];
#pragma unroll
    for (int nt = 0; nt < 4; ++nt) acc[nt] = (f32x4){0.f, 0.f, 0.f, 0.f};
#pragma unroll
    for (int nt = 0; nt < 4; ++nt)
#pragma unroll
      for (int kk = 0; kk < 8; ++kk)
        acc[nt] = __builtin_amdgcn_mfma_f32_16x16x32_bf16(a[kk], breg[nt][kk], acc[nt], 0, 0, 0);

    int row0 = t * 16;
#pragma unroll
    for (int nt = 0; nt < 4; ++nt) {
      int col = col0 + nt * 16 + ncol;
#pragma unroll
      for (int r = 0; r < 4; ++r) {
        int row = row0 + rgrp + r;
        if (row < M) {
          float v = acc[nt][r] + bv[nt];
          out[(size_t)row * D + col] = (v >= 0.f) ? v : 0.2f * v;
        }
      }
    }

#pragma unroll
    for (int kk = 0; kk < 8; ++kk) a[kk] = an[kk];
  }
}

extern "C" void kernel_launch(void* const* d_in, const int* in_sizes, int n_in,
                              void* d_out, int out_size, void* d_ws, size_t ws_size,
                              hipStream_t stream) {
  const float* x = (const float*)d_in[0];
  const int* ei = (const int*)d_in[1];
  const float* W = (const float*)d_in[2];
  const float* b = (const float*)d_in[3];
  float* out = (float*)d_out;

  const int N = in_sizes[0] / D;
  const int E = in_sizes[1] / 2;
  const int* row = ei;
  const int* col = ei + E;

  char* ws = (char*)d_ws;
  size_t off = 0;
  auto alloc = [&](size_t bytes) -> void* {
    void* p = ws + off;
    off += (bytes + 255) & ~(size_t)255;
    return p;
  };
  auto align256 = [](size_t v) { return (v + 255) & ~(size_t)255; };

  int* offsets = (int*)alloc((size_t)(N + 1) * 4);
  float* dinv = (float*)alloc((size_t)N * 4);
  int* csr_col = (int*)alloc((size_t)E * 4);
  char* hreg = (char*)alloc((size_t)N * D * 2);  // h; early phase hosts sorted/counts/bases
  __hip_bfloat16* Wt = (__hip_bfloat16*)alloc((size_t)D * D * 2);
  size_t tail_off = off;  // union: xb (fast) | deg+partials+rank (fallback)

  const int NCBK = (N + 1023) >> 10;       // coarse buckets (1024 rows)
  const int ncb = (N + 8191) >> 13;        // col windows
  const int nblk = (E + CH - 1) / CH;
  const int total8 = N * D / 8;
  const int convb = (total8 + 255) / 256;

  size_t s_sorted = 0;
  size_t s_counts = s_sorted + align256((size_t)E * 4);
  size_t s_base = s_counts + align256((size_t)NCBK * nblk * 4);
  size_t s_total = s_base + align256((size_t)(NCBK + 1) * 4);
  size_t h_need = s_total + (size_t)NCBK * 4;

  size_t fast_need = tail_off + align256((size_t)N * D * 2);
  bool use_fast = (N <= 122880) && (NCBK <= 128) && (ncb <= MAXNCB) && (nblk <= 512) &&
                  (h_need <= (size_t)N * D * 2) && (fast_need <= ws_size);

  unsigned short* h = (unsigned short*)hreg;

  if (use_fast) {
    unsigned int* sorted = (unsigned int*)(hreg + s_sorted);
    int* counts = (int*)(hreg + s_counts);
    int* bucket_base = (int*)(hreg + s_base);
    int* total = (int*)(hreg + s_total);
    uint4* xb0 = (uint4*)(ws + tail_off);
    uint4* xb1 = xb0 + (size_t)N * 16;

    fused_prep_kernel<<<nblk + convb + D, 256, 0, stream>>>(
        row, x, W, xb0, xb1, Wt, counts, E, NCBK, nblk, total8, convb);
    colscan_kernel<<<NCBK, 256, 0, stream>>>(counts, total, nblk);
    bucket_scan_kernel<<<1, 256, 0, stream>>>(total, bucket_base, NCBK);
    scatter_kernel<<<nblk, 256, 0, stream>>>(row, col, counts, bucket_base, sorted, E, NCBK, nblk);
    bucket_csr_kernel<<<NCBK, 512, 0, stream>>>(sorted, bucket_base, offsets, dinv, csr_col,
                                                N, E, NCBK, ncb);
    spmm_half_kernel<<<(N + 3) / 4, 256, 0, stream>>>(offsets, csr_col, dinv, xb0, (uint4*)h, N, 0);
    spmm_half_kernel<<<(N + 3) / 4, 256, 0, stream>>>(offsets, csr_col, dinv, xb1, (uint4*)h, N, 16);
  } else {
    size_t foff = tail_off;
    int* deg = (int*)(ws + foff); foff += align256((size_t)N * 4);
    int* partials = (int*)(ws + foff); foff += align256(512 * 4);
    unsigned short* rank = (unsigned short*)(ws + foff); foff += align256((size_t)E * 2);
    (void)hipMemsetAsync(deg, 0, (size_t)N * 4, stream);
    const int eb = (E + 255) / 256;
    const int nb = (N + 255) / 256;
    deg_rank_kernel<<<eb, 256, 0, stream>>>(row, deg, rank, E);
    fscan1<<<nb, 256, 0, stream>>>(deg, offsets, partials, N);
    fscan2<<<1, 512, 0, stream>>>(partials, nb);
    fscan3<<<nb, 256, 0, stream>>>(offsets, partials, deg, dinv, N, E);
    fill_kernel<<<eb, 256, 0, stream>>>(row, col, offsets, rank, csr_col, E);
    wt_kernel<<<D, D, 0, stream>>>(W, Wt);
    spmm_f32_kernel<<<(N + 3) / 4, 256, 0, stream>>>(offsets, csr_col, dinv, x, h, N);
  }
  const int ntiles = (N + 15) / 16;
  int gB = ntiles < 512 ? ntiles : 512;
  gemm_kernel<<<gB, 256, 0, stream>>>((const __hip_bfloat16*)h, Wt, b, out, N, ntiles);
}

// Round 9
// 372.843 us; speedup vs baseline: 1.3900x; 1.0279x over previous
//
#include <hip/hip_runtime.h>
#include <hip/hip_bf16.h>

#define D 256
#define CH 8192     // edges per count/scatter block
#define MAXNCB 15   // max col-windows (N <= 122880)
#define BROW 256    // rows per bucket

typedef __attribute__((ext_vector_type(8))) short bf16x8;
typedef __attribute__((ext_vector_type(4))) float f32x4;

static __device__ __forceinline__ unsigned int f2bf(float f) {
  __hip_bfloat16 b = __float2bfloat16(f);
  return (unsigned int)*reinterpret_cast<unsigned short*>(&b);
}
static __device__ __forceinline__ float u2f(unsigned int u) {
  return __uint_as_float(u);
}

static __device__ __forceinline__ void acc8w(float* acc, uint4 v, float wt) {
  acc[0] += wt * u2f(v.x << 16);
  acc[1] += wt * u2f(v.x & 0xffff0000u);
  acc[2] += wt * u2f(v.y << 16);
  acc[3] += wt * u2f(v.y & 0xffff0000u);
  acc[4] += wt * u2f(v.z << 16);
  acc[5] += wt * u2f(v.z & 0xffff0000u);
  acc[6] += wt * u2f(v.w << 16);
  acc[7] += wt * u2f(v.w & 0xffff0000u);
}

// ============ FAST BUILD: two-level counting sort (256-row buckets) ============

// K1 fused: [0,nblk) bucket count | [nblk,nblk+convb) x->bf16 stripes | [+,+D) W^T
// counts layout: bucket-major counts[t * nblk + blk]
__global__ __launch_bounds__(256) void fused_prep_kernel(
    const int* __restrict__ row, const float* __restrict__ x, const float* __restrict__ W,
    uint4* __restrict__ xb0, uint4* __restrict__ xb1, __hip_bfloat16* __restrict__ Wt,
    int* __restrict__ counts, int E, int NCBK, int nblk, int total8, int convb) {
  __shared__ int hist[512];
  int bid = blockIdx.x, tid = threadIdx.x;
  if (bid < nblk) {
    for (int t = tid; t < NCBK; t += 256) hist[t] = 0;
    __syncthreads();
    int e0 = bid * CH, e1 = min(E, e0 + CH);
    for (int e = e0 + tid; e < e1; e += 256) atomicAdd(&hist[row[e] >> 8], 1);
    __syncthreads();
    for (int t = tid; t < NCBK; t += 256) counts[(size_t)t * nblk + bid] = hist[t];
  } else if (bid < nblk + convb) {
    int idx = (bid - nblk) * 256 + tid;
    if (idx < total8) {
      int j = idx >> 5, k8 = idx & 31;
      const float4* x4 = reinterpret_cast<const float4*>(x);
      float4 a = x4[(size_t)idx * 2], bb = x4[(size_t)idx * 2 + 1];
      uint4 o;
      o.x = f2bf(a.x) | (f2bf(a.y) << 16);
      o.y = f2bf(a.z) | (f2bf(a.w) << 16);
      o.z = f2bf(bb.x) | (f2bf(bb.y) << 16);
      o.w = f2bf(bb.z) | (f2bf(bb.w) << 16);
      uint4* dst = (k8 < 16) ? xb0 : xb1;
      dst[(size_t)j * 16 + (k8 & 15)] = o;
    }
  } else {
    int n = bid - nblk - convb;  // 0..D-1
    Wt[n * D + tid] = __float2bfloat16(W[tid * D + n]);
  }
}

// K2a: per-bucket exclusive scan over its nblk entries (one block per bucket)
__global__ __launch_bounds__(256) void colscan_kernel(int* __restrict__ counts,
                                                      int* __restrict__ total, int nblk) {
  __shared__ int a[512], bb[512];
  int t = blockIdx.x, tid = threadIdx.x;
  int* base = counts + (size_t)t * nblk;
  int v0[2];
  for (int k = 0; k < 2; ++k) {
    int i = tid + k * 256;
    v0[k] = (i < nblk) ? base[i] : 0;
    a[i] = v0[k];
  }
  __syncthreads();
  int* cur = a;
  int* nxt = bb;
  for (int off = 1; off < 512; off <<= 1) {
    for (int k = 0; k < 2; ++k) {
      int i = tid + k * 256;
      int v = cur[i];
      if (i >= off) v += cur[i - off];
      nxt[i] = v;
    }
    __syncthreads();
    int* tmp = cur; cur = nxt; nxt = tmp;
  }
  for (int k = 0; k < 2; ++k) {
    int i = tid + k * 256;
    if (i < nblk) {
      base[i] = cur[i] - v0[k];  // exclusive
      if (i == nblk - 1) total[t] = cur[i];
    }
  }
}

// K2b: scan bucket totals -> bucket_base[NCBK+1] (NCBK <= 512)
__global__ void bucket_scan_kernel(const int* __restrict__ total, int* __restrict__ bucket_base,
                                   int NCBK) {
  __shared__ int a[512], bb[512];
  int t = threadIdx.x;  // 512 threads
  a[t] = (t < NCBK) ? total[t] : 0;
  __syncthreads();
  int* cur = a;
  int* nxt = bb;
  for (int off = 1; off < 512; off <<= 1) {
    int v = cur[t];
    if (t >= off) v += cur[t - off];
    nxt[t] = v;
    __syncthreads();
    int* tmp = cur; cur = nxt; nxt = tmp;
  }
  if (t == 0) bucket_base[0] = 0;
  if (t < NCBK) bucket_base[t + 1] = cur[t];
}

// K3: scatter into bucket order; pack (row&255)<<17 | col
__global__ __launch_bounds__(256) void scatter_kernel(
    const int* __restrict__ row, const int* __restrict__ col, const int* __restrict__ counts,
    const int* __restrict__ bucket_base, unsigned int* __restrict__ sorted, int E, int NCBK,
    int nblk) {
  __shared__ int base[512];
  __shared__ int cur[512];
  int bid = blockIdx.x, tid = threadIdx.x;
  for (int t = tid; t < NCBK; t += 256) {
    base[t] = bucket_base[t] + counts[(size_t)t * nblk + bid];
    cur[t] = 0;
  }
  __syncthreads();
  int e0 = bid * CH, e1 = min(E, e0 + CH);
  for (int e = e0 + tid; e < e1; e += 256) {
    int r = row[e], c = col[e];
    int b = r >> 8;
    int p = base[b] + atomicAdd(&cur[b], 1);
    sorted[p] = ((unsigned int)(r & 255) << 17) | (unsigned int)c;
  }
}

// K4: per 256-node bucket: LDS (node, col>>13) count + parallel scan -> offsets/dinv/csr_col
__global__ __launch_bounds__(256) void bucket_csr_kernel(
    const unsigned int* __restrict__ sorted, const int* __restrict__ bucket_base,
    int* __restrict__ offsets, float* __restrict__ dinv, int* __restrict__ csr_col,
    int N, int E, int NCBK, int ncb) {
  __shared__ int cnt[BROW * MAXNCB];
  __shared__ int auxa[256], auxb[256];
  int b = blockIdx.x, tid = threadIdx.x;
  int lo = bucket_base[b], hi = bucket_base[b + 1];
  int slots = BROW * ncb;
  for (int t = tid; t < slots; t += 256) cnt[t] = 0;
  __syncthreads();
  for (int e = lo + tid; e < hi; e += 256) {
    unsigned int v = sorted[e];
    atomicAdd(&cnt[(v >> 17) * ncb + ((v & 0x1FFFFu) >> 13)], 1);
  }
  __syncthreads();
  // parallel exclusive scan of cnt[0..slots)
  int per = (slots + 255) / 256;
  int i0 = tid * per;
  int run = 0;
  for (int k = 0; k < per; ++k) {
    int i = i0 + k;
    if (i < slots) {
      int c = cnt[i];
      cnt[i] = run;
      run += c;
    }
  }
  auxa[tid] = run;
  __syncthreads();
  int* cur = auxa;
  int* nxt = auxb;
  for (int off = 1; off < 256; off <<= 1) {
    int v = cur[tid];
    if (tid >= off) v += cur[tid - off];
    nxt[tid] = v;
    __syncthreads();
    int* tmp = cur; cur = nxt; nxt = tmp;
  }
  int add = (tid > 0) ? cur[tid - 1] : 0;
  for (int k = 0; k < per; ++k) {
    int i = i0 + k;
    if (i < slots) cnt[i] += add;
  }
  __syncthreads();
  // offsets + dinv
  if (tid < BROW) {
    int gr = b * BROW + tid;
    if (gr < N) {
      int start = cnt[tid * ncb];
      int nxt_s = (tid == BROW - 1) ? (hi - lo) : cnt[(tid + 1) * ncb];
      int dg = nxt_s - start;
      offsets[gr] = lo + start;
      dinv[gr] = (dg > 0) ? rsqrtf((float)dg) : 0.f;
    }
  }
  if (b == NCBK - 1 && tid == 0) offsets[N] = E;
  __syncthreads();
  for (int e = lo + tid; e < hi; e += 256) {
    unsigned int v = sorted[e];
    int p = lo + atomicAdd(&cnt[(v >> 17) * ncb + ((v & 0x1FFFFu) >> 13)], 1);
    csr_col[p] = (int)(v & 0x1FFFFu);
  }
}

// ============ SpMM (bf16 stripes, per-edge dinv weight) ============
__global__ __launch_bounds__(256) void spmm_half_kernel(
    const int* __restrict__ offsets, const int* __restrict__ csr_col,
    const float* __restrict__ dinv, const uint4* __restrict__ xb,
    uint4* __restrict__ h, int N, int hoff) {
  int wave = threadIdx.x >> 6;
  int lane = threadIdx.x & 63;
  int i = blockIdx.x * 4 + wave;
  if (i >= N) return;
  int g = lane >> 4;  // edge group 0..3
  int l = lane & 15;  // 8-feature chunk within stripe
  int beg = offsets[i], end = offsets[i + 1];

  float acc[8];
#pragma unroll
  for (int j = 0; j < 8; ++j) acc[j] = 0.f;

  int e = beg + g;
  for (; e + 12 < end; e += 16) {
    int c0 = csr_col[e], c1 = csr_col[e + 4], c2 = csr_col[e + 8], c3 = csr_col[e + 12];
    float w0 = dinv[c0], w1 = dinv[c1], w2 = dinv[c2], w3 = dinv[c3];
    uint4 v0 = xb[(size_t)c0 * 16 + l];
    uint4 v1 = xb[(size_t)c1 * 16 + l];
    uint4 v2 = xb[(size_t)c2 * 16 + l];
    uint4 v3 = xb[(size_t)c3 * 16 + l];
    acc8w(acc, v0, w0);
    acc8w(acc, v1, w1);
    acc8w(acc, v2, w2);
    acc8w(acc, v3, w3);
  }
  for (; e < end; e += 4) {
    int c = csr_col[e];
    float w = dinv[c];
    uint4 v = xb[(size_t)c * 16 + l];
    acc8w(acc, v, w);
  }

#pragma unroll
  for (int j = 0; j < 8; ++j) {
    acc[j] += __shfl(acc[j], lane ^ 16, 64);
    acc[j] += __shfl(acc[j], lane ^ 32, 64);
  }

  if (g == 0) {
    float di = dinv[i];
    uint4 o;
    o.x = f2bf(acc[0] * di) | (f2bf(acc[1] * di) << 16);
    o.y = f2bf(acc[2] * di) | (f2bf(acc[3] * di) << 16);
    o.z = f2bf(acc[4] * di) | (f2bf(acc[5] * di) << 16);
    o.w = f2bf(acc[6] * di) | (f2bf(acc[7] * di) << 16);
    h[(size_t)i * 32 + hoff + l] = o;
  }
}

// ============ FALLBACK build (atomic) ============
__global__ void deg_rank_kernel(const int* __restrict__ row, int* __restrict__ deg,
                                unsigned short* __restrict__ rank, int E) {
  int e = blockIdx.x * blockDim.x + threadIdx.x;
  if (e < E) rank[e] = (unsigned short)atomicAdd(&deg[row[e]], 1);
}
__global__ void fscan1(const int* __restrict__ deg, int* __restrict__ offsets,
                       int* __restrict__ partials, int n) {
  __shared__ int tmp[256];
  int i = blockIdx.x * 256 + threadIdx.x;
  int v = (i < n) ? deg[i] : 0;
  tmp[threadIdx.x] = v;
  __syncthreads();
  for (int off = 1; off < 256; off <<= 1) {
    int t = (threadIdx.x >= off) ? tmp[threadIdx.x - off] : 0;
    __syncthreads();
    tmp[threadIdx.x] += t;
    __syncthreads();
  }
  if (i < n) offsets[i] = tmp[threadIdx.x] - v;
  if (threadIdx.x == 255) partials[blockIdx.x] = tmp[255];
}
__global__ void fscan2(int* __restrict__ partials, int nb) {
  __shared__ int tmp[512];
  int tid = threadIdx.x;
  int v = (tid < nb) ? partials[tid] : 0;
  tmp[tid] = v;
  __syncthreads();
  for (int off = 1; off < 512; off <<= 1) {
    int t = (tid >= off) ? tmp[tid - off] : 0;
    __syncthreads();
    tmp[tid] += t;
    __syncthreads();
  }
  if (tid < nb) partials[tid] = tmp[tid] - v;
}
__global__ void fscan3(int* __restrict__ offsets, const int* __restrict__ partials,
                       const int* __restrict__ deg, float* __restrict__ dinv, int n, int E) {
  int i = blockIdx.x * 256 + threadIdx.x;
  if (i < n) {
    offsets[i] += partials[blockIdx.x];
    int d = deg[i];
    dinv[i] = (d > 0) ? rsqrtf((float)d) : 0.0f;
    if (i == 0) offsets[n] = E;
  }
}
__global__ void fill_kernel(const int* __restrict__ row, const int* __restrict__ col,
                            const int* __restrict__ offsets, const unsigned short* __restrict__ rank,
                            int* __restrict__ csr_col, int E) {
  int e = blockIdx.x * blockDim.x + threadIdx.x;
  if (e < E) {
    int pos = offsets[row[e]] + (int)rank[e];
    csr_col[pos] = col[e];
  }
}
__global__ void wt_kernel(const float* __restrict__ W, __hip_bfloat16* __restrict__ Wt) {
  int n = blockIdx.x, k = threadIdx.x;
  Wt[n * D + k] = __float2bfloat16(W[k * D + n]);
}
__global__ __launch_bounds__(256) void spmm_f32_kernel(
    const int* __restrict__ offsets, const int* __restrict__ csr_col,
    const float* __restrict__ dinv, const float* __restrict__ x,
    unsigned short* __restrict__ h, int N) {
  int wave = threadIdx.x >> 6;
  int lane = threadIdx.x & 63;
  int i = blockIdx.x * 4 + wave;
  if (i >= N) return;
  int beg = offsets[i], end = offsets[i + 1];
  float di = dinv[i];
  const float4* x4 = reinterpret_cast<const float4*>(x);
  float4 acc = make_float4(0.f, 0.f, 0.f, 0.f);
  for (int e = beg; e < end; ++e) {
    int c = csr_col[e];
    float w = di * dinv[c];
    float4 v = x4[(size_t)c * 64 + lane];
    acc.x += w * v.x; acc.y += w * v.y; acc.z += w * v.z; acc.w += w * v.w;
  }
  ushort4 o;
  o.x = (unsigned short)f2bf(acc.x);
  o.y = (unsigned short)f2bf(acc.y);
  o.z = (unsigned short)f2bf(acc.z);
  o.w = (unsigned short)f2bf(acc.w);
  *reinterpret_cast<ushort4*>(h + (size_t)i * D + lane * 4) = o;
}

// ============ GEMM: W register-resident, grid-stride over 16-row tiles ============
__global__ __launch_bounds__(256, 2) void gemm_kernel(
    const __hip_bfloat16* __restrict__ h, const __hip_bfloat16* __restrict__ Wt,
    const float* __restrict__ bias, float* __restrict__ out, int M, int ntiles) {
  const int tid = threadIdx.x;
  const int wave = tid >> 6;   // col-slice [wave*64, wave*64+64)
  const int lane = tid & 63;
  const int ncol = lane & 15;
  const int kgrp = (lane >> 4) * 8;
  const int rgrp = (lane >> 4) * 4;
  const int col0 = wave * 64;

  const short* hp = reinterpret_cast<const short*>(h);
  const short* wtp = reinterpret_cast<const short*>(Wt);

  bf16x8 breg[4][8];
#pragma unroll
  for (int nt = 0; nt < 4; ++nt)
#pragma unroll
    for (int kk = 0; kk < 8; ++kk)
      breg[nt][kk] =
          *reinterpret_cast<const bf16x8*>(wtp + (size_t)(col0 + nt * 16 + ncol) * D + kk * 32 + kgrp);

  float bv[4];
#pragma unroll
  for (int nt = 0; nt < 4; ++nt) bv[nt] = bias[col0 + nt * 16 + ncol];

  const int stride = gridDim.x;
  int t = blockIdx.x;
  if (t >= ntiles) return;

  bf16x8 a[8];
  {
    int arow = t * 16 + (lane & 15);
    int arow_c = (arow < M) ? arow : 0;
#pragma unroll
    for (int kk = 0; kk < 8; ++kk)
      a[kk] = *reinterpret_cast<const bf16x8*>(hp + (size_t)arow_c * D + kk * 32 + kgrp);
  }

  for (; t < ntiles; t += stride) {
    int tn = t + stride;
    bf16x8 an[8];
    if (tn < ntiles) {
      int arow = tn * 16 + (lane & 15);
      int arow_c = (arow < M) ? arow : 0;
#pragma unroll
      for (int kk = 0; kk < 8; ++kk)
        an[kk] = *reinterpret_cast<const bf16x8*>(hp + (size_t)arow_c * D + kk * 32 + kgrp);
    }

    f32x4 acc[4];
#pragma unroll
    for (int nt = 0; nt < 4; ++nt) acc[nt] = (f32x4){0.f, 0.f, 0.f, 0.f};
#pragma unroll
    for (int nt = 0; nt < 4; ++nt)
#pragma unroll
      for (int kk = 0; kk < 8; ++kk)
        acc[nt] = __builtin_amdgcn_mfma_f32_16x16x32_bf16(a[kk], breg[nt][kk], acc[nt], 0, 0, 0);

    int row0 = t * 16;
#pragma unroll
    for (int nt = 0; nt < 4; ++nt) {
      int col = col0 + nt * 16 + ncol;
#pragma unroll
      for (int r = 0; r < 4; ++r) {
        int row = row0 + rgrp + r;
        if (row < M) {
          float v = acc[nt][r] + bv[nt];
          out[(size_t)row * D + col] = (v >= 0.f) ? v : 0.2f * v;
        }
      }
    }

#pragma unroll
    for (int kk = 0; kk < 8; ++kk) a[kk] = an[kk];
  }
}

extern "C" void kernel_launch(void* const* d_in, const int* in_sizes, int n_in,
                              void* d_out, int out_size, void* d_ws, size_t ws_size,
                              hipStream_t stream) {
  const float* x = (const float*)d_in[0];
  const int* ei = (const int*)d_in[1];
  const float* W = (const float*)d_in[2];
  const float* b = (const float*)d_in[3];
  float* out = (float*)d_out;

  const int N = in_sizes[0] / D;
  const int E = in_sizes[1] / 2;
  const int* row = ei;
  const int* col = ei + E;

  char* ws = (char*)d_ws;
  size_t off = 0;
  auto alloc = [&](size_t bytes) -> void* {
    void* p = ws + off;
    off += (bytes + 255) & ~(size_t)255;
    return p;
  };
  auto align256 = [](size_t v) { return (v + 255) & ~(size_t)255; };

  int* offsets = (int*)alloc((size_t)(N + 1) * 4);
  float* dinv = (float*)alloc((size_t)N * 4);
  int* csr_col = (int*)alloc((size_t)E * 4);
  char* hreg = (char*)alloc((size_t)N * D * 2);  // h; early phase hosts sorted/counts/bases
  __hip_bfloat16* Wt = (__hip_bfloat16*)alloc((size_t)D * D * 2);
  size_t tail_off = off;  // union: xb (fast) | deg+partials+rank (fallback)

  const int NCBK = (N + BROW - 1) / BROW;  // 256-row buckets
  const int ncb = (N + 8191) >> 13;        // col windows
  const int nblk = (E + CH - 1) / CH;
  const int total8 = N * D / 8;
  const int convb = (total8 + 255) / 256;

  size_t s_sorted = 0;
  size_t s_counts = s_sorted + align256((size_t)E * 4);
  size_t s_base = s_counts + align256((size_t)NCBK * nblk * 4);
  size_t s_total = s_base + align256((size_t)(NCBK + 1) * 4);
  size_t h_need = s_total + (size_t)NCBK * 4;

  size_t fast_need = tail_off + align256((size_t)N * D * 2);
  bool use_fast = (N <= 122880) && (NCBK <= 512) && (ncb <= MAXNCB) && (nblk <= 512) &&
                  (h_need <= (size_t)N * D * 2) && (fast_need <= ws_size);

  unsigned short* h = (unsigned short*)hreg;

  if (use_fast) {
    unsigned int* sorted = (unsigned int*)(hreg + s_sorted);
    int* counts = (int*)(hreg + s_counts);
    int* bucket_base = (int*)(hreg + s_base);
    int* total = (int*)(hreg + s_total);
    uint4* xb0 = (uint4*)(ws + tail_off);
    uint4* xb1 = xb0 + (size_t)N * 16;

    fused_prep_kernel<<<nblk + convb + D, 256, 0, stream>>>(
        row, x, W, xb0, xb1, Wt, counts, E, NCBK, nblk, total8, convb);
    colscan_kernel<<<NCBK, 256, 0, stream>>>(counts, total, nblk);
    bucket_scan_kernel<<<1, 512, 0, stream>>>(total, bucket_base, NCBK);
    scatter_kernel<<<nblk, 256, 0, stream>>>(row, col, counts, bucket_base, sorted, E, NCBK, nblk);
    bucket_csr_kernel<<<NCBK, 256, 0, stream>>>(sorted, bucket_base, offsets, dinv, csr_col,
                                                N, E, NCBK, ncb);
    spmm_half_kernel<<<(N + 3) / 4, 256, 0, stream>>>(offsets, csr_col, dinv, xb0, (uint4*)h, N, 0);
    spmm_half_kernel<<<(N + 3) / 4, 256, 0, stream>>>(offsets, csr_col, dinv, xb1, (uint4*)h, N, 16);
  } else {
    size_t foff = tail_off;
    int* deg = (int*)(ws + foff); foff += align256((size_t)N * 4);
    int* partials = (int*)(ws + foff); foff += align256(512 * 4);
    unsigned short* rank = (unsigned short*)(ws + foff); foff += align256((size_t)E * 2);
    (void)hipMemsetAsync(deg, 0, (size_t)N * 4, stream);
    const int eb = (E + 255) / 256;
    const int nb = (N + 255) / 256;
    deg_rank_kernel<<<eb, 256, 0, stream>>>(row, deg, rank, E);
    fscan1<<<nb, 256, 0, stream>>>(deg, offsets, partials, N);
    fscan2<<<1, 512, 0, stream>>>(partials, nb);
    fscan3<<<nb, 256, 0, stream>>>(offsets, partials, deg, dinv, N, E);
    fill_kernel<<<eb, 256, 0, stream>>>(row, col, offsets, rank, csr_col, E);
    wt_kernel<<<D, D, 0, stream>>>(W, Wt);
    spmm_f32_kernel<<<(N + 3) / 4, 256, 0, stream>>>(offsets, csr_col, dinv, x, h, N);
  }
  const int ntiles = (N + 15) / 16;
  int gB = ntiles < 512 ? ntiles : 512;
  gemm_kernel<<<gB, 256, 0, stream>>>((const __hip_bfloat16*)h, Wt, b, out, N, ntiles);
}

// Round 10
// 371.656 us; speedup vs baseline: 1.3945x; 1.0032x over previous
//
#include <hip/hip_runtime.h>
#include <hip/hip_bf16.h>

#define D 256
#define CH 8192     // edges per count/scatter block
#define MAXNCB 15   // max col-windows (N <= 122880)
#define BROW 256    // rows per bucket

typedef __attribute__((ext_vector_type(8))) short bf16x8;
typedef __attribute__((ext_vector_type(4))) float f32x4;

static __device__ __forceinline__ unsigned int f2bf(float f) {
  __hip_bfloat16 b = __float2bfloat16(f);
  return (unsigned int)*reinterpret_cast<unsigned short*>(&b);
}
static __device__ __forceinline__ float u2f(unsigned int u) {
  return __uint_as_float(u);
}

static __device__ __forceinline__ void acc8w(float* acc, uint4 v, float wt) {
  acc[0] += wt * u2f(v.x << 16);
  acc[1] += wt * u2f(v.x & 0xffff0000u);
  acc[2] += wt * u2f(v.y << 16);
  acc[3] += wt * u2f(v.y & 0xffff0000u);
  acc[4] += wt * u2f(v.z << 16);
  acc[5] += wt * u2f(v.z & 0xffff0000u);
  acc[6] += wt * u2f(v.w << 16);
  acc[7] += wt * u2f(v.w & 0xffff0000u);
}

// bijective XCD-chunk swizzle: physical XCD (b%8) gets a contiguous logical range
static __device__ __forceinline__ int xcd_swizzle(int b, int nwg) {
  int xcd = b & 7;
  int idx = b >> 3;
  int q = nwg >> 3, r = nwg & 7;
  return (xcd < r) ? (xcd * (q + 1) + idx) : (r * (q + 1) + (xcd - r) * q + idx);
}

// ============ FAST BUILD: two-level counting sort (256-row buckets) ============

// K1 fused: [0,nblk) bucket count | [nblk,nblk+convb) x->bf16 stripes | [+,+D) W^T
// counts layout: bucket-major counts[t * nblk + blk]
__global__ __launch_bounds__(256) void fused_prep_kernel(
    const int* __restrict__ row, const float* __restrict__ x, const float* __restrict__ W,
    uint4* __restrict__ xb0, uint4* __restrict__ xb1, __hip_bfloat16* __restrict__ Wt,
    int* __restrict__ counts, int E, int NCBK, int nblk, int total8, int convb) {
  __shared__ int hist[512];
  int bid = blockIdx.x, tid = threadIdx.x;
  if (bid < nblk) {
    for (int t = tid; t < NCBK; t += 256) hist[t] = 0;
    __syncthreads();
    int e0 = bid * CH, e1 = min(E, e0 + CH);
    for (int e = e0 + tid; e < e1; e += 256) atomicAdd(&hist[row[e] >> 8], 1);
    __syncthreads();
    for (int t = tid; t < NCBK; t += 256) counts[(size_t)t * nblk + bid] = hist[t];
  } else if (bid < nblk + convb) {
    int idx = (bid - nblk) * 256 + tid;
    if (idx < total8) {
      int j = idx >> 5, k8 = idx & 31;
      const float4* x4 = reinterpret_cast<const float4*>(x);
      float4 a = x4[(size_t)idx * 2], bb = x4[(size_t)idx * 2 + 1];
      uint4 o;
      o.x = f2bf(a.x) | (f2bf(a.y) << 16);
      o.y = f2bf(a.z) | (f2bf(a.w) << 16);
      o.z = f2bf(bb.x) | (f2bf(bb.y) << 16);
      o.w = f2bf(bb.z) | (f2bf(bb.w) << 16);
      uint4* dst = (k8 < 16) ? xb0 : xb1;
      dst[(size_t)j * 16 + (k8 & 15)] = o;
    }
  } else {
    int n = bid - nblk - convb;  // 0..D-1
    Wt[n * D + tid] = __float2bfloat16(W[tid * D + n]);
  }
}

// K2a: per-bucket exclusive scan over its nblk entries (one block per bucket)
__global__ __launch_bounds__(256) void colscan_kernel(int* __restrict__ counts,
                                                      int* __restrict__ total, int nblk) {
  __shared__ int a[512], bb[512];
  int t = blockIdx.x, tid = threadIdx.x;
  int* base = counts + (size_t)t * nblk;
  int v0[2];
  for (int k = 0; k < 2; ++k) {
    int i = tid + k * 256;
    v0[k] = (i < nblk) ? base[i] : 0;
    a[i] = v0[k];
  }
  __syncthreads();
  int* cur = a;
  int* nxt = bb;
  for (int off = 1; off < 512; off <<= 1) {
    for (int k = 0; k < 2; ++k) {
      int i = tid + k * 256;
      int v = cur[i];
      if (i >= off) v += cur[i - off];
      nxt[i] = v;
    }
    __syncthreads();
    int* tmp = cur; cur = nxt; nxt = tmp;
  }
  for (int k = 0; k < 2; ++k) {
    int i = tid + k * 256;
    if (i < nblk) {
      base[i] = cur[i] - v0[k];  // exclusive
      if (i == nblk - 1) total[t] = cur[i];
    }
  }
}

// K2b: scan bucket totals -> bucket_base[NCBK+1] (NCBK <= 512)
__global__ void bucket_scan_kernel(const int* __restrict__ total, int* __restrict__ bucket_base,
                                   int NCBK) {
  __shared__ int a[512], bb[512];
  int t = threadIdx.x;  // 512 threads
  a[t] = (t < NCBK) ? total[t] : 0;
  __syncthreads();
  int* cur = a;
  int* nxt = bb;
  for (int off = 1; off < 512; off <<= 1) {
    int v = cur[t];
    if (t >= off) v += cur[t - off];
    nxt[t] = v;
    __syncthreads();
    int* tmp = cur; cur = nxt; nxt = tmp;
  }
  if (t == 0) bucket_base[0] = 0;
  if (t < NCBK) bucket_base[t + 1] = cur[t];
}

// K3: scatter into bucket order; pack (row&255)<<17 | col
__global__ __launch_bounds__(256) void scatter_kernel(
    const int* __restrict__ row, const int* __restrict__ col, const int* __restrict__ counts,
    const int* __restrict__ bucket_base, unsigned int* __restrict__ sorted, int E, int NCBK,
    int nblk) {
  __shared__ int base[512];
  __shared__ int cur[512];
  int bid = blockIdx.x, tid = threadIdx.x;
  for (int t = tid; t < NCBK; t += 256) {
    base[t] = bucket_base[t] + counts[(size_t)t * nblk + bid];
    cur[t] = 0;
  }
  __syncthreads();
  int e0 = bid * CH, e1 = min(E, e0 + CH);
  for (int e = e0 + tid; e < e1; e += 256) {
    int r = row[e], c = col[e];
    int b = r >> 8;
    int p = base[b] + atomicAdd(&cur[b], 1);
    sorted[p] = ((unsigned int)(r & 255) << 17) | (unsigned int)c;
  }
}

// K4: per 256-node bucket: LDS (node, col>>13) count + parallel scan -> offsets/dinv/csr_col
__global__ __launch_bounds__(256) void bucket_csr_kernel(
    const unsigned int* __restrict__ sorted, const int* __restrict__ bucket_base,
    int* __restrict__ offsets, float* __restrict__ dinv, int* __restrict__ csr_col,
    int N, int E, int NCBK, int ncb) {
  __shared__ int cnt[BROW * MAXNCB];
  __shared__ int auxa[256], auxb[256];
  int b = blockIdx.x, tid = threadIdx.x;
  int lo = bucket_base[b], hi = bucket_base[b + 1];
  int slots = BROW * ncb;
  for (int t = tid; t < slots; t += 256) cnt[t] = 0;
  __syncthreads();
  for (int e = lo + tid; e < hi; e += 256) {
    unsigned int v = sorted[e];
    atomicAdd(&cnt[(v >> 17) * ncb + ((v & 0x1FFFFu) >> 13)], 1);
  }
  __syncthreads();
  // parallel exclusive scan of cnt[0..slots)
  int per = (slots + 255) / 256;
  int i0 = tid * per;
  int run = 0;
  for (int k = 0; k < per; ++k) {
    int i = i0 + k;
    if (i < slots) {
      int c = cnt[i];
      cnt[i] = run;
      run += c;
    }
  }
  auxa[tid] = run;
  __syncthreads();
  int* cur = auxa;
  int* nxt = auxb;
  for (int off = 1; off < 256; off <<= 1) {
    int v = cur[tid];
    if (tid >= off) v += cur[tid - off];
    nxt[tid] = v;
    __syncthreads();
    int* tmp = cur; cur = nxt; nxt = tmp;
  }
  int add = (tid > 0) ? cur[tid - 1] : 0;
  for (int k = 0; k < per; ++k) {
    int i = i0 + k;
    if (i < slots) cnt[i] += add;
  }
  __syncthreads();
  // offsets + dinv
  if (tid < BROW) {
    int gr = b * BROW + tid;
    if (gr < N) {
      int start = cnt[tid * ncb];
      int nxt_s = (tid == BROW - 1) ? (hi - lo) : cnt[(tid + 1) * ncb];
      int dg = nxt_s - start;
      offsets[gr] = lo + start;
      dinv[gr] = (dg > 0) ? rsqrtf((float)dg) : 0.f;
    }
  }
  if (b == NCBK - 1 && tid == 0) offsets[N] = E;
  __syncthreads();
  for (int e = lo + tid; e < hi; e += 256) {
    unsigned int v = sorted[e];
    int p = lo + atomicAdd(&cnt[(v >> 17) * ncb + ((v & 0x1FFFFu) >> 13)], 1);
    csr_col[p] = (int)(v & 0x1FFFFu);
  }
}

// ============ SpMM (bf16 stripes, per-edge dinv weight, XCD-chunked swizzle) ============
__global__ __launch_bounds__(256) void spmm_half_kernel(
    const int* __restrict__ offsets, const int* __restrict__ csr_col,
    const float* __restrict__ dinv, const uint4* __restrict__ xb,
    uint4* __restrict__ h, int N, int hoff) {
  int wave = threadIdx.x >> 6;
  int lane = threadIdx.x & 63;
  int blk = xcd_swizzle(blockIdx.x, gridDim.x);
  int i = blk * 4 + wave;
  if (i >= N) return;
  int g = lane >> 4;  // edge group 0..3
  int l = lane & 15;  // 8-feature chunk within stripe
  int beg = offsets[i], end = offsets[i + 1];

  float acc[8];
#pragma unroll
  for (int j = 0; j < 8; ++j) acc[j] = 0.f;

  int e = beg + g;
  for (; e + 12 < end; e += 16) {
    int c0 = csr_col[e], c1 = csr_col[e + 4], c2 = csr_col[e + 8], c3 = csr_col[e + 12];
    float w0 = dinv[c0], w1 = dinv[c1], w2 = dinv[c2], w3 = dinv[c3];
    uint4 v0 = xb[(size_t)c0 * 16 + l];
    uint4 v1 = xb[(size_t)c1 * 16 + l];
    uint4 v2 = xb[(size_t)c2 * 16 + l];
    uint4 v3 = xb[(size_t)c3 * 16 + l];
    acc8w(acc, v0, w0);
    acc8w(acc, v1, w1);
    acc8w(acc, v2, w2);
    acc8w(acc, v3, w3);
  }
  for (; e < end; e += 4) {
    int c = csr_col[e];
    float w = dinv[c];
    uint4 v = xb[(size_t)c * 16 + l];
    acc8w(acc, v, w);
  }

#pragma unroll
  for (int j = 0; j < 8; ++j) {
    acc[j] += __shfl(acc[j], lane ^ 16, 64);
    acc[j] += __shfl(acc[j], lane ^ 32, 64);
  }

  if (g == 0) {
    float di = dinv[i];
    uint4 o;
    o.x = f2bf(acc[0] * di) | (f2bf(acc[1] * di) << 16);
    o.y = f2bf(acc[2] * di) | (f2bf(acc[3] * di) << 16);
    o.z = f2bf(acc[4] * di) | (f2bf(acc[5] * di) << 16);
    o.w = f2bf(acc[6] * di) | (f2bf(acc[7] * di) << 16);
    h[(size_t)i * 32 + hoff + l] = o;
  }
}

// ============ FALLBACK build (atomic) ============
__global__ void deg_rank_kernel(const int* __restrict__ row, int* __restrict__ deg,
                                unsigned short* __restrict__ rank, int E) {
  int e = blockIdx.x * blockDim.x + threadIdx.x;
  if (e < E) rank[e] = (unsigned short)atomicAdd(&deg[row[e]], 1);
}
__global__ void fscan1(const int* __restrict__ deg, int* __restrict__ offsets,
                       int* __restrict__ partials, int n) {
  __shared__ int tmp[256];
  int i = blockIdx.x * 256 + threadIdx.x;
  int v = (i < n) ? deg[i] : 0;
  tmp[threadIdx.x] = v;
  __syncthreads();
  for (int off = 1; off < 256; off <<= 1) {
    int t = (threadIdx.x >= off) ? tmp[threadIdx.x - off] : 0;
    __syncthreads();
    tmp[threadIdx.x] += t;
    __syncthreads();
  }
  if (i < n) offsets[i] = tmp[threadIdx.x] - v;
  if (threadIdx.x == 255) partials[blockIdx.x] = tmp[255];
}
__global__ void fscan2(int* __restrict__ partials, int nb) {
  __shared__ int tmp[512];
  int tid = threadIdx.x;
  int v = (tid < nb) ? partials[tid] : 0;
  tmp[tid] = v;
  __syncthreads();
  for (int off = 1; off < 512; off <<= 1) {
    int t = (tid >= off) ? tmp[tid - off] : 0;
    __syncthreads();
    tmp[tid] += t;
    __syncthreads();
  }
  if (tid < nb) partials[tid] = tmp[tid] - v;
}
__global__ void fscan3(int* __restrict__ offsets, const int* __restrict__ partials,
                       const int* __restrict__ deg, float* __restrict__ dinv, int n, int E) {
  int i = blockIdx.x * 256 + threadIdx.x;
  if (i < n) {
    offsets[i] += partials[blockIdx.x];
    int d = deg[i];
    dinv[i] = (d > 0) ? rsqrtf((float)d) : 0.0f;
    if (i == 0) offsets[n] = E;
  }
}
__global__ void fill_kernel(const int* __restrict__ row, const int* __restrict__ col,
                            const int* __restrict__ offsets, const unsigned short* __restrict__ rank,
                            int* __restrict__ csr_col, int E) {
  int e = blockIdx.x * blockDim.x + threadIdx.x;
  if (e < E) {
    int pos = offsets[row[e]] + (int)rank[e];
    csr_col[pos] = col[e];
  }
}
__global__ void wt_kernel(const float* __restrict__ W, __hip_bfloat16* __restrict__ Wt) {
  int n = blockIdx.x, k = threadIdx.x;
  Wt[n * D + k] = __float2bfloat16(W[k * D + n]);
}
__global__ __launch_bounds__(256) void spmm_f32_kernel(
    const int* __restrict__ offsets, const int* __restrict__ csr_col,
    const float* __restrict__ dinv, const float* __restrict__ x,
    unsigned short* __restrict__ h, int N) {
  int wave = threadIdx.x >> 6;
  int lane = threadIdx.x & 63;
  int i = blockIdx.x * 4 + wave;
  if (i >= N) return;
  int beg = offsets[i], end = offsets[i + 1];
  float di = dinv[i];
  const float4* x4 = reinterpret_cast<const float4*>(x);
  float4 acc = make_float4(0.f, 0.f, 0.f, 0.f);
  for (int e = beg; e < end; ++e) {
    int c = csr_col[e];
    float w = di * dinv[c];
    float4 v = x4[(size_t)c * 64 + lane];
    acc.x += w * v.x; acc.y += w * v.y; acc.z += w * v.z; acc.w += w * v.w;
  }
  ushort4 o;
  o.x = (unsigned short)f2bf(acc.x);
  o.y = (unsigned short)f2bf(acc.y);
  o.z = (unsigned short)f2bf(acc.z);
  o.w = (unsigned short)f2bf(acc.w);
  *reinterpret_cast<ushort4*>(h + (size_t)i * D + lane * 4) = o;
}

// ============ GEMM: W register-resident, grid-stride over 16-row tiles ============
__global__ __launch_bounds__(256, 2) void gemm_kernel(
    const __hip_bfloat16* __restrict__ h, const __hip_bfloat16* __restrict__ Wt,
    const float* __restrict__ bias, float* __restrict__ out, int M, int ntiles) {
  const int tid = threadIdx.x;
  const int wave = tid >> 6;   // col-slice [wave*64, wave*64+64)
  const int lane = tid & 63;
  const int ncol = lane & 15;
  const int kgrp = (lane >> 4) * 8;
  const int rgrp = (lane >> 4) * 4;
  const int col0 = wave * 64;

  const short* hp = reinterpret_cast<const short*>(h);
  const short* wtp = reinterpret_cast<const short*>(Wt);

  bf16x8 breg[4][8];
#pragma unroll
  for (int nt = 0; nt < 4; ++nt)
#pragma unroll
    for (int kk = 0; kk < 8; ++kk)
      breg[nt][kk] =
          *reinterpret_cast<const bf16x8*>(wtp + (size_t)(col0 + nt * 16 + ncol) * D + kk * 32 + kgrp);

  float bv[4];
#pragma unroll
  for (int nt = 0; nt < 4; ++nt) bv[nt] = bias[col0 + nt * 16 + ncol];

  const int stride = gridDim.x;
  int t = blockIdx.x;
  if (t >= ntiles) return;

  bf16x8 a[8];
  {
    int arow = t * 16 + (lane & 15);
    int arow_c = (arow < M) ? arow : 0;
#pragma unroll
    for (int kk = 0; kk < 8; ++kk)
      a[kk] = *reinterpret_cast<const bf16x8*>(hp + (size_t)arow_c * D + kk * 32 + kgrp);
  }

  for (; t < ntiles; t += stride) {
    int tn = t + stride;
    bf16x8 an[8];
    if (tn < ntiles) {
      int arow = tn * 16 + (lane & 15);
      int arow_c = (arow < M) ? arow : 0;
#pragma unroll
      for (int kk = 0; kk < 8; ++kk)
        an[kk] = *reinterpret_cast<const bf16x8*>(hp + (size_t)arow_c * D + kk * 32 + kgrp);
    }

    f32x4 acc[4];
#pragma unroll
    for (int nt = 0; nt < 4; ++nt) acc[nt] = (f32x4){0.f, 0.f, 0.f, 0.f};
#pragma unroll
    for (int nt = 0; nt < 4; ++nt)
#pragma unroll
      for (int kk = 0; kk < 8; ++kk)
        acc[nt] = __builtin_amdgcn_mfma_f32_16x16x32_bf16(a[kk], breg[nt][kk], acc[nt], 0, 0, 0);

    int row0 = t * 16;
#pragma unroll
    for (int nt = 0; nt < 4; ++nt) {
      int col = col0 + nt * 16 + ncol;
#pragma unroll
      for (int r = 0; r < 4; ++r) {
        int row = row0 + rgrp + r;
        if (row < M) {
          float v = acc[nt][r] + bv[nt];
          out[(size_t)row * D + col] = (v >= 0.f) ? v : 0.2f * v;
        }
      }
    }

#pragma unroll
    for (int kk = 0; kk < 8; ++kk) a[kk] = an[kk];
  }
}

extern "C" void kernel_launch(void* const* d_in, const int* in_sizes, int n_in,
                              void* d_out, int out_size, void* d_ws, size_t ws_size,
                              hipStream_t stream) {
  const float* x = (const float*)d_in[0];
  const int* ei = (const int*)d_in[1];
  const float* W = (const float*)d_in[2];
  const float* b = (const float*)d_in[3];
  float* out = (float*)d_out;

  const int N = in_sizes[0] / D;
  const int E = in_sizes[1] / 2;
  const int* row = ei;
  const int* col = ei + E;

  char* ws = (char*)d_ws;
  size_t off = 0;
  auto alloc = [&](size_t bytes) -> void* {
    void* p = ws + off;
    off += (bytes + 255) & ~(size_t)255;
    return p;
  };
  auto align256 = [](size_t v) { return (v + 255) & ~(size_t)255; };

  int* offsets = (int*)alloc((size_t)(N + 1) * 4);
  float* dinv = (float*)alloc((size_t)N * 4);
  int* csr_col = (int*)alloc((size_t)E * 4);
  char* hreg = (char*)alloc((size_t)N * D * 2);  // h; early phase hosts sorted/counts/bases
  __hip_bfloat16* Wt = (__hip_bfloat16*)alloc((size_t)D * D * 2);
  size_t tail_off = off;  // union: xb (fast) | deg+partials+rank (fallback)

  const int NCBK = (N + BROW - 1) / BROW;  // 256-row buckets
  const int ncb = (N + 8191) >> 13;        // col windows
  const int nblk = (E + CH - 1) / CH;
  const int total8 = N * D / 8;
  const int convb = (total8 + 255) / 256;

  size_t s_sorted = 0;
  size_t s_counts = s_sorted + align256((size_t)E * 4);
  size_t s_base = s_counts + align256((size_t)NCBK * nblk * 4);
  size_t s_total = s_base + align256((size_t)(NCBK + 1) * 4);
  size_t h_need = s_total + (size_t)NCBK * 4;

  size_t fast_need = tail_off + align256((size_t)N * D * 2);
  bool use_fast = (N <= 122880) && (NCBK <= 512) && (ncb <= MAXNCB) && (nblk <= 512) &&
                  (h_need <= (size_t)N * D * 2) && (fast_need <= ws_size);

  unsigned short* h = (unsigned short*)hreg;

  if (use_fast) {
    unsigned int* sorted = (unsigned int*)(hreg + s_sorted);
    int* counts = (int*)(hreg + s_counts);
    int* bucket_base = (int*)(hreg + s_base);
    int* total = (int*)(hreg + s_total);
    uint4* xb0 = (uint4*)(ws + tail_off);
    uint4* xb1 = xb0 + (size_t)N * 16;

    fused_prep_kernel<<<nblk + convb + D, 256, 0, stream>>>(
        row, x, W, xb0, xb1, Wt, counts, E, NCBK, nblk, total8, convb);
    colscan_kernel<<<NCBK, 256, 0, stream>>>(counts, total, nblk);
    bucket_scan_kernel<<<1, 512, 0, stream>>>(total, bucket_base, NCBK);
    scatter_kernel<<<nblk, 256, 0, stream>>>(row, col, counts, bucket_base, sorted, E, NCBK, nblk);
    bucket_csr_kernel<<<NCBK, 256, 0, stream>>>(sorted, bucket_base, offsets, dinv, csr_col,
                                                N, E, NCBK, ncb);
    spmm_half_kernel<<<(N + 3) / 4, 256, 0, stream>>>(offsets, csr_col, dinv, xb0, (uint4*)h, N, 0);
    spmm_half_kernel<<<(N + 3) / 4, 256, 0, stream>>>(offsets, csr_col, dinv, xb1, (uint4*)h, N, 16);
  } else {
    size_t foff = tail_off;
    int* deg = (int*)(ws + foff); foff += align256((size_t)N * 4);
    int* partials = (int*)(ws + foff); foff += align256(512 * 4);
    unsigned short* rank = (unsigned short*)(ws + foff); foff += align256((size_t)E * 2);
    (void)hipMemsetAsync(deg, 0, (size_t)N * 4, stream);
    const int eb = (E + 255) / 256;
    const int nb = (N + 255) / 256;
    deg_rank_kernel<<<eb, 256, 0, stream>>>(row, deg, rank, E);
    fscan1<<<nb, 256, 0, stream>>>(deg, offsets, partials, N);
    fscan2<<<1, 512, 0, stream>>>(partials, nb);
    fscan3<<<nb, 256, 0, stream>>>(offsets, partials, deg, dinv, N, E);
    fill_kernel<<<eb, 256, 0, stream>>>(row, col, offsets, rank, csr_col, E);
    wt_kernel<<<D, D, 0, stream>>>(W, Wt);
    spmm_f32_kernel<<<(N + 3) / 4, 256, 0, stream>>>(offsets, csr_col, dinv, x, h, N);
  }
  const int ntiles = (N + 15) / 16;
  int gB = ntiles < 512 ? ntiles : 512;
  gemm_kernel<<<gB, 256, 0, stream>>>((const __hip_bfloat16*)h, Wt, b, out, N, ntiles);
}